// Round 25
// baseline (291.339 us; speedup 1.0000x reference)
//
#include <hip/hip_runtime.h>
#include <hip/hip_bf16.h>
#include <math.h>

typedef unsigned short u16;
typedef unsigned int   u32;
typedef unsigned long long u64;
typedef __attribute__((ext_vector_type(8))) short short8v;
typedef __attribute__((ext_vector_type(4))) float f32x4;

__device__ __forceinline__ float bf2f(u16 u) {
  union { u32 i; float f; } v; v.i = ((u32)u) << 16; return v.f;
}
__device__ __forceinline__ u16 f2bf(float f) {  // round-to-nearest-even
  union { float f; u32 i; } v; v.f = f;
  u32 r = (v.i + 0x7FFFu + ((v.i >> 16) & 1u)) >> 16;
  return (u16)r;
}

// ---------------- conv1 + bn1 + relu + maxpool2 via MFMA im2col (K=32, hi/lo input split)
// T2 XOR chunk swizzle on sA*/sB* (write chunk = logical ^ (row&3); read likewise)
__global__ __launch_bounds__(256, 2) void k_conv1m(
    const float* __restrict__ x,
    const u16* __restrict__ wh, const u16* __restrict__ wl,
    const float* __restrict__ cb, const float* __restrict__ g, const float* __restrict__ bb,
    u16* __restrict__ feat1, int b0)
{
  __shared__ __align__(16) u16 sInH[3*18*18], sInL[3*18*18];
  __shared__ __align__(16) u16 sAh[256*40], sAl[256*40];
  __shared__ __align__(16) u16 sBh[64*40],  sBl[64*40];
  __shared__ float sBias[64];
  const int tx = blockIdx.x, ty = blockIdx.y, bl = blockIdx.z;
  const int b = b0 + bl;
  const int y0 = ty*16, x0 = tx*16;
  const int tid = threadIdx.x;
  const int w = tid >> 6, l = tid & 63, lr = l & 15, lk = l >> 4;

  if (tid < 64) {
    float sc = g[tid] * rsqrtf(1.0f + 1e-5f);
    sBias[tid] = cb[tid] * sc + bb[tid];
  }
  {
    const int oc = tid >> 2, seg = tid & 3;
    const int ps = seg ^ (oc & 3);           // swizzled chunk
    *reinterpret_cast<uint4*>(&sBh[oc*40 + ps*8]) =
        *reinterpret_cast<const uint4*>(wh + oc*32 + seg*8);
    *reinterpret_cast<uint4*>(&sBl[oc*40 + ps*8]) =
        *reinterpret_cast<const uint4*>(wl + oc*32 + seg*8);
  }
  for (int i = tid; i < 3*18*18; i += 256) {
    const int c = i / 324, r = (i / 18) % 18, q = i % 18;
    const int yy = y0 - 1 + r, xx = x0 - 1 + q;
    float v = 0.f;
    if (yy >= 0 && yy < 256 && xx >= 0 && xx < 256)
      v = x[(((size_t)b*3 + c)*256 + yy)*256 + xx];
    const u16 h = f2bf(v);
    sInH[i] = h;
    sInL[i] = f2bf(v - bf2f(h));
  }
  __syncthreads();
  {
    const int py = tid >> 4, px = tid & 15;
    u32 hw[16], lw[16];
    #pragma unroll
    for (int i = 0; i < 16; i++) { hw[i] = 0u; lw[i] = 0u; }
    #pragma unroll
    for (int c = 0; c < 3; c++)
      #pragma unroll
      for (int ky = 0; ky < 3; ky++)
        #pragma unroll
        for (int kx = 0; kx < 3; kx++) {
          const int k = c*9 + ky*3 + kx;
          const int src = (c*18 + py + ky)*18 + px + kx;
          hw[k >> 1] |= ((u32)sInH[src]) << ((k & 1)*16);
          lw[k >> 1] |= ((u32)sInL[src]) << ((k & 1)*16);
        }
    #pragma unroll
    for (int s = 0; s < 4; s++) {
      const int ps = s ^ (tid & 3);          // swizzled chunk
      uint4 vh, vl;
      vh.x = hw[s*4+0]; vh.y = hw[s*4+1]; vh.z = hw[s*4+2]; vh.w = hw[s*4+3];
      vl.x = lw[s*4+0]; vl.y = lw[s*4+1]; vl.z = lw[s*4+2]; vl.w = lw[s*4+3];
      *reinterpret_cast<uint4*>(&sAh[tid*40 + ps*8]) = vh;
      *reinterpret_cast<uint4*>(&sAl[tid*40 + ps*8]) = vl;
    }
  }
  __syncthreads();
  f32x4 acc[4][4];
  #pragma unroll
  for (int j = 0; j < 4; j++)
    #pragma unroll
    for (int ct = 0; ct < 4; ct++)
      acc[j][ct] = (f32x4){0.f,0.f,0.f,0.f};
  const int lkA = lk ^ (lr & 3);             // swizzled read chunk (pix&3 == lr&3)
  #pragma unroll
  for (int j = 0; j < 4; j++) {
    const int mt = w*4 + j;
    const short8v ah = *reinterpret_cast<const short8v*>(&sAh[(mt*16 + lr)*40 + lkA*8]);
    const short8v al = *reinterpret_cast<const short8v*>(&sAl[(mt*16 + lr)*40 + lkA*8]);
    #pragma unroll
    for (int ct = 0; ct < 4; ct++) {
      const short8v bh = *reinterpret_cast<const short8v*>(&sBh[(ct*16 + lr)*40 + lkA*8]);
      const short8v bv = *reinterpret_cast<const short8v*>(&sBl[(ct*16 + lr)*40 + lkA*8]);
      acc[j][ct] = __builtin_amdgcn_mfma_f32_16x16x32_bf16(ah, bh, acc[j][ct], 0, 0, 0);
      acc[j][ct] = __builtin_amdgcn_mfma_f32_16x16x32_bf16(ah, bv, acc[j][ct], 0, 0, 0);
      acc[j][ct] = __builtin_amdgcn_mfma_f32_16x16x32_bf16(al, bh, acc[j][ct], 0, 0, 0);
    }
  }
  #pragma unroll
  for (int j = 0; j < 2; j++) {
    const int jA = 2*j, jB = 2*j + 1;
    const int oy = ty*8 + w*2 + j;
    #pragma unroll
    for (int xh = 0; xh < 2; xh++) {
      const int ox = tx*8 + lk*2 + xh;
      #pragma unroll
      for (int ct = 0; ct < 4; ct++) {
        const int oc = ct*16 + lr;
        float m = fmaxf(fmaxf(acc[jA][ct][2*xh], acc[jA][ct][2*xh+1]),
                        fmaxf(acc[jB][ct][2*xh], acc[jB][ct][2*xh+1]));
        m = fmaxf(m + sBias[oc], 0.f);
        feat1[(((size_t)bl*128 + oy)*128 + ox)*64 + oc] = f2bf(m);
      }
    }
  }
}

// ---------------- conv2 + bn2 + relu + maxpool2 via MFMA implicit GEMM (B dbuf, T2 swizzle)
__global__ __launch_bounds__(256, 2) void k_conv2m(
    const u16* __restrict__ feat1,
    const u16* __restrict__ wh, const u16* __restrict__ wl,
    const float* __restrict__ cb, const float* __restrict__ g, const float* __restrict__ bb,
    u16* __restrict__ feat2)
{
  __shared__ __align__(16) u16 sA[18*34*40];
  __shared__ __align__(16) u16 sBh[2][64*40], sBl[2][64*40];
  __shared__ float sBias[64];
  const int tx = blockIdx.x, ty = blockIdx.y, bl = blockIdx.z;
  const int y0 = ty*16, x0 = tx*32;
  const int tid = threadIdx.x;
  const int w = tid >> 6, l = tid & 63;
  const int lr = l & 15, lk = l >> 4;

  if (tid < 64) {
    float sc = g[tid] * rsqrtf(1.0f + 1e-5f);
    sBias[tid] = cb[tid] * sc + bb[tid];
  }

  f32x4 acc[8][4];
  #pragma unroll
  for (int j = 0; j < 8; j++)
    #pragma unroll
    for (int ct = 0; ct < 4; ct++)
      acc[j][ct] = (f32x4){0.f,0.f,0.f,0.f};

  const int ocB = tid >> 2;
  const int psB = (tid & 3) ^ (ocB & 3);     // swizzled B chunk
  uint4 rBh, rBl;
  auto ldB = [&](int chunk, int kk) {
    const size_t src = (size_t)(kk*2 + chunk)*2048 + tid*8;
    rBh = *reinterpret_cast<const uint4*>(wh + src);
    rBl = *reinterpret_cast<const uint4*>(wl + src);
  };
  auto stB = [&](int buf) {
    *reinterpret_cast<uint4*>(&sBh[buf][ocB*40 + psB*8]) = rBh;
    *reinterpret_cast<uint4*>(&sBl[buf][ocB*40 + psB*8]) = rBl;
  };

  const int lkB = lk ^ (lr & 3);             // swizzled B read chunk
  for (int chunk = 0; chunk < 2; chunk++) {
    __syncthreads();
    ldB(chunk, 0);
    for (int idx = tid; idx < 612*4; idx += 256) {
      const int pix = idx >> 2, seg = idx & 3;
      const int r = pix / 34, cc = pix % 34;
      const int yy = y0 - 1 + r, xx = x0 - 1 + cc;
      uint4 v = {0u,0u,0u,0u};
      if (yy >= 0 && yy < 128 && xx >= 0 && xx < 128)
        v = *reinterpret_cast<const uint4*>(
              feat1 + (((size_t)bl*128 + yy)*128 + xx)*64 + chunk*32 + seg*8);
      const int ps = seg ^ (pix & 3);        // swizzled A chunk
      *reinterpret_cast<uint4*>(&sA[(size_t)pix*40 + ps*8]) = v;
    }
    stB(0);
    __syncthreads();
    int cur = 0;
    for (int kk = 0; kk < 9; kk++) {
      if (kk + 1 < 9) ldB(chunk, kk + 1);
      const int ky = kk / 3, kx = kk % 3;
      short8v a[8];
      #pragma unroll
      for (int j = 0; j < 8; j++) {
        const int m = w*8 + j;
        const int r = (m >> 1) + ky;
        const int cc = (m & 1)*16 + lr + kx;
        const int pixR = r*34 + cc;
        const int lkR = lk ^ (pixR & 3);     // swizzled A read chunk
        a[j] = *reinterpret_cast<const short8v*>(&sA[(size_t)pixR*40 + lkR*8]);
      }
      #pragma unroll
      for (int ct = 0; ct < 4; ct++) {
        const short8v bh = *reinterpret_cast<const short8v*>(&sBh[cur][(ct*16 + lr)*40 + lkB*8]);
        const short8v bv = *reinterpret_cast<const short8v*>(&sBl[cur][(ct*16 + lr)*40 + lkB*8]);
        #pragma unroll
        for (int j = 0; j < 8; j++) {
          acc[j][ct] = __builtin_amdgcn_mfma_f32_16x16x32_bf16(a[j], bh, acc[j][ct], 0, 0, 0);
          acc[j][ct] = __builtin_amdgcn_mfma_f32_16x16x32_bf16(a[j], bv, acc[j][ct], 0, 0, 0);
        }
      }
      if (kk + 1 < 9) {
        stB(cur ^ 1);
        __syncthreads();
        cur ^= 1;
      }
    }
  }
  #pragma unroll
  for (int u = 0; u < 2; u++) {
    #pragma unroll
    for (int xh = 0; xh < 2; xh++) {
      const int jA = 4*u + xh, jB = 4*u + 2 + xh;
      #pragma unroll
      for (int ct = 0; ct < 4; ct++) {
        const int oc = ct*16 + lr;
        const float bias = sBias[oc];
        const float v0 = fmaxf(fmaxf(acc[jA][ct][0], acc[jA][ct][1]),
                               fmaxf(acc[jB][ct][0], acc[jB][ct][1]));
        const float v1 = fmaxf(fmaxf(acc[jA][ct][2], acc[jA][ct][3]),
                               fmaxf(acc[jB][ct][2], acc[jB][ct][3]));
        const u16 b0v = f2bf(fmaxf(v0 + bias, 0.f));
        const u16 b1v = f2bf(fmaxf(v1 + bias, 0.f));
        const int py = ty*8 + 2*w + u;
        const int px = tx*16 + xh*8 + lk*2;
        u32 pk = (u32)b0v | ((u32)b1v << 16);
        *reinterpret_cast<u32*>(&feat2[(((size_t)bl*64 + oc)*64 + py)*64 + px]) = pk;
      }
    }
  }
}

// ---------------- adjacency phase 2: mask2 = rows of (adj@adj>0) minus diagonal
__global__ __launch_bounds__(256) void k_adj2(
    const int* __restrict__ nbr1, u64* __restrict__ mask2)
{
  const int i = threadIdx.x;
  if (i >= 225) return;
  u64 m0=0, m1=0, m2=0, m3=0;
  #pragma unroll
  for (int t = 0; t < 8; t++) {
    const int tt = nbr1[i*8 + t];
    #pragma unroll
    for (int u = 0; u < 8; u++) {
      const int j = nbr1[tt*8 + u];
      const u64 bset = 1ull << (j & 63);
      const int wd = j >> 6;
      m0 |= (wd == 0) ? bset : 0ull;
      m1 |= (wd == 1) ? bset : 0ull;
      m2 |= (wd == 2) ? bset : 0ull;
      m3 |= (wd == 3) ? bset : 0ull;
    }
  }
  {
    const u64 bc = ~(1ull << (i & 63));
    const int wd = i >> 6;
    if (wd == 0) m0 &= bc; else if (wd == 1) m1 &= bc;
    else if (wd == 2) m2 &= bc; else m3 &= bc;
  }
  mask2[i*4+0] = m0; mask2[i*4+1] = m1; mask2[i*4+2] = m2; mask2[i*4+3] = m3;
}

// ---------------- fused weight prep + adjacency 8-NN (blocks >= 1688)
__global__ __launch_bounds__(256) void k_prep(
    const float* __restrict__ pjw, u16* __restrict__ pwh, u16* __restrict__ pwl,
    const float* __restrict__ c2w, const float* __restrict__ bn2g,
    u16* __restrict__ wc2h, u16* __restrict__ wc2l,
    const float* __restrict__ c1w, const float* __restrict__ bn1g,
    u16* __restrict__ wc1h, u16* __restrict__ wc1l,
    const float* __restrict__ ipw, float* __restrict__ iwt,
    const float* __restrict__ opw, float* __restrict__ owt,
    const float* __restrict__ f1w, float* __restrict__ f1wt,
    const float* __restrict__ f2w, float* __restrict__ f2wt,
    const float* __restrict__ w1w, float* __restrict__ w1t,
    const float* __restrict__ w2w, float* __restrict__ w2t,
    const float* __restrict__ gw,  float* __restrict__ gwt,
    int* __restrict__ nbr1)
{
  __shared__ int skey[256];
  __shared__ int sred[256];
  const int blk = blockIdx.x, tid = threadIdx.x;
  if (blk < 512) {
    const int i = (blk*256 + tid) * 4;
    float4 v = *reinterpret_cast<const float4*>(pjw + i);
    float e[4] = {v.x, v.y, v.z, v.w};
    ushort4 h, l;
    u16* hp = &h.x; u16* lp = &l.x;
    #pragma unroll
    for (int j = 0; j < 4; j++) {
      u16 hb = f2bf(e[j]);
      hp[j] = hb;
      lp[j] = f2bf(e[j] - bf2f(hb));
    }
    *reinterpret_cast<ushort4*>(pwh + i) = h;
    *reinterpret_cast<ushort4*>(pwl + i) = l;
  } else if (blk < 656) {
    const int d = (blk - 512)*256 + tid;
    if (d < 36864) {
      const int icL = d & 31, oc = (d >> 5) & 63, chunk = (d >> 11) & 1, kk = d >> 12;
      const float sc = bn2g[oc] * rsqrtf(1.0f + 1e-5f);
      const float val = c2w[((size_t)oc*64 + chunk*32 + icL)*9 + kk] * sc;
      const u16 hb = f2bf(val);
      wc2h[d] = hb;
      wc2l[d] = f2bf(val - bf2f(hb));
    }
  } else if (blk < 664) {
    const int d = (blk - 656)*256 + tid;
    if (d < 2048) {
      const int k = d & 31, oc = d >> 5;
      float val = 0.f;
      if (k < 27) val = c1w[oc*27 + k] * (bn1g[oc] * rsqrtf(1.0f + 1e-5f));
      const u16 hb = f2bf(val);
      wc1h[d] = hb;
      wc1l[d] = f2bf(val - bf2f(hb));
    }
  } else if (blk < 1688) {
    const float* src; float* dst; int O, K, base;
    if      (blk <  856) { src = ipw; dst = iwt;  O = 384; K = 128; base = 664;  }
    else if (blk <  920) { src = opw; dst = owt;  O = 128; K = 128; base = 856;  }
    else if (blk < 1176) { src = f1w; dst = f1wt; O = 512; K = 128; base = 920;  }
    else if (blk < 1432) { src = f2w; dst = f2wt; O = 128; K = 512; base = 1176; }
    else if (blk < 1496) { src = w1w; dst = w1t;  O = 128; K = 128; base = 1432; }
    else if (blk < 1560) { src = w2w; dst = w2t;  O = 128; K = 128; base = 1496; }
    else                 { src = gw;  dst = gwt;  O = 128; K = 256; base = 1560; }
    const int idx = (blk - base)*256 + tid;
    if (idx < O * K) {
      const int o = idx / K, k = idx % K;
      dst[(size_t)k * O + o] = src[idx];
    }
  } else {
    const int i = blk - 1688;
    int key = 0x7FFFFFFF;
    if (tid < 225 && tid != i) {
      const int di = i/15 - tid/15, dj = i%15 - tid%15;
      key = (di*di + dj*dj)*256 + tid;
    }
    skey[tid] = key;
    __syncthreads();
    for (int t = 0; t < 8; t++) {
      sred[tid] = skey[tid];
      __syncthreads();
      #pragma unroll
      for (int st = 128; st > 0; st >>= 1) {
        if (tid < st) sred[tid] = min(sred[tid], sred[tid+st]);
        __syncthreads();
      }
      const int wj = sred[0] & 255;
      if (tid == 0) nbr1[i*8 + t] = wj;
      __syncthreads();
      if (tid == wj) skey[tid] = 0x7FFFFFFF;
      __syncthreads();
    }
  }
}

// ---------------- patch-projection MFMA GEMM, split-K=8, 32-row M-tiles, ct split
// across wave pairs (grid 8x8x16 = 1024 blocks -> 4 blocks/CU), A prefetched 1 step
__global__ __launch_bounds__(256, 4) void k_projm(
    const u16* __restrict__ feat2,
    const u16* __restrict__ pwh, const u16* __restrict__ pwl,
    float* __restrict__ partial, int b0)
{
  __shared__ __align__(16) u16 sBh[2][128*40];
  __shared__ __align__(16) u16 sBl[2][128*40];
  const int cx = blockIdx.x, kc = blockIdx.y, bl = blockIdx.z;
  const int b  = b0 + bl;
  const int n0 = cx * 32;
  const int rows = (225 - n0) < 32 ? (225 - n0) : 32;
  const int tid = threadIdx.x;
  const int w = tid >> 6, l = tid & 63;
  const int lr = l & 15, lk = l >> 4;
  const int wr = w & 1;                      // row-half of block tile
  const int wc = w >> 1;                     // col-half: ct in [wc*4, wc*4+4)

  f32x4 acc[4];
  #pragma unroll
  for (int i = 0; i < 4; i++) acc[i] = (f32x4){0.f, 0.f, 0.f, 0.f};

  int an = n0 + wr*16 + lr;
  if (an > 224) an = 224;
  const int aph = an / 15, apw = an % 15;
  const int kbeg = kc * 512, kend = kbeg + 512;

  uint4 rBh[2], rBl[2];
  auto ldB = [&](int k0) {
    #pragma unroll
    for (int p = 0; p < 2; p++) {
      const int idx = p*256 + tid;
      const int col = idx >> 2, seg = idx & 3;
      const size_t off = (size_t)col*4096 + k0 + seg*8;
      rBh[p] = *reinterpret_cast<const uint4*>(pwh + off);
      rBl[p] = *reinterpret_cast<const uint4*>(pwl + off);
    }
  };
  auto stB = [&](int buf) {
    #pragma unroll
    for (int p = 0; p < 2; p++) {
      const int idx = p*256 + tid;
      const int col = idx >> 2, seg = idx & 3;
      const int ps = seg ^ (col & 3);        // swizzled chunk
      *reinterpret_cast<uint4*>(&sBh[buf][col*40 + ps*8]) = rBh[p];
      *reinterpret_cast<uint4*>(&sBl[buf][col*40 + ps*8]) = rBl[p];
    }
  };
  auto ldA = [&](int k0, uint2& a0, uint2& a1) {
    const int c = k0 >> 6;
    const int i = ((k0 & 32) >> 3) + lk;
    const u16* ap = feat2 + (((size_t)bl*64 + c)*64 + aph*4 + i)*64 + apw*4;
    a0 = *reinterpret_cast<const uint2*>(ap);
    a1 = *reinterpret_cast<const uint2*>(ap + 4);
  };

  const int lkB = lk ^ (lr & 3);             // swizzled read chunk
  uint2 a0c, a1c, a0n, a1n;
  ldB(kbeg);
  ldA(kbeg, a0c, a1c);
  stB(0);
  __syncthreads();
  int cur = 0;
  for (int k0 = kbeg; k0 < kend; k0 += 32) {
    const bool more = (k0 + 32 < kend);
    if (more) { ldB(k0 + 32); ldA(k0 + 32, a0n, a1n); }
    union { short8v v; uint2 u[2]; } a;
    a.u[0] = a0c; a.u[1] = a1c;
    #pragma unroll
    for (int c4 = 0; c4 < 4; c4++) {
      const int ct = wc*4 + c4;
      const short8v bh = *reinterpret_cast<const short8v*>(&sBh[cur][(ct*16 + lr)*40 + lkB*8]);
      const short8v bv = *reinterpret_cast<const short8v*>(&sBl[cur][(ct*16 + lr)*40 + lkB*8]);
      acc[c4] = __builtin_amdgcn_mfma_f32_16x16x32_bf16(a.v, bh, acc[c4], 0, 0, 0);
      acc[c4] = __builtin_amdgcn_mfma_f32_16x16x32_bf16(a.v, bv, acc[c4], 0, 0, 0);
    }
    if (more) {
      stB(cur ^ 1);
      __syncthreads();
      cur ^= 1;
      a0c = a0n; a1c = a1n;
    }
  }
  #pragma unroll
  for (int c4 = 0; c4 < 4; c4++) {
    const int col = (wc*4 + c4)*16 + lr;
    #pragma unroll
    for (int v = 0; v < 4; v++) {
      const int r = wr*16 + lk*4 + v;
      if (r < rows)
        partial[(((size_t)kc*16 + b)*225 + n0 + r)*128 + col] = acc[c4][v];
    }
  }
}

// ---------------- reduce split-K partials + bias -> nodes
__global__ __launch_bounds__(128) void k_projr(
    const float* __restrict__ partial, const float* __restrict__ pb,
    float* __restrict__ nodes, int b0)
{
  const int n = blockIdx.x, bl = blockIdx.y;
  const int b = b0 + bl;
  const int d = threadIdx.x;
  float s = pb[d];
  #pragma unroll
  for (int kc = 0; kc < 8; kc++)
    s += partial[(((size_t)kc*16 + b)*225 + n)*128 + d];
  nodes[((size_t)b*225 + n)*128 + d] = s;
}

// ---------------- FUSED gather + z1/z2/gate/score: 4 rows per block (900 blocks)
__global__ __launch_bounds__(256) void k_gz2(
    const float* __restrict__ nodes, const int* __restrict__ nbr1,
    const u64* __restrict__ mask2,
    const float* __restrict__ w1t, const float* __restrict__ w1b,
    const float* __restrict__ w2t, const float* __restrict__ w2b,
    const float* __restrict__ gwt, const float* __restrict__ gb,
    const float* __restrict__ sw, const float* __restrict__ sb,
    float* __restrict__ zbuf, float* __restrict__ scores)
{
  __shared__ float sA1[4][128], sA2[4][128], sC[4][256], sRed[4][128];
  const int row0 = blockIdx.x * 4;
  const int tid = threadIdx.x;
  const int d = tid & 127, rr = tid >> 7;
  #pragma unroll
  for (int q = 0; q < 2; q++) {
    const int lrow = rr*2 + q;
    const int row = row0 + lrow;
    const int b = row / 225, n = row % 225;
    const float* nb = nodes + (size_t)b * 225 * 128;
    float a1 = 0.f;
    #pragma unroll
    for (int t = 0; t < 8; t++) a1 += nb[(size_t)nbr1[n*8+t]*128 + d];
    float a2 = 0.f;
    for (int wd = 0; wd < 4; wd++) {
      u64 m = mask2[n*4 + wd];
      while (m) {
        int j = wd*64 + __builtin_ctzll(m);
        a2 += nb[(size_t)j*128 + d];
        m &= m - 1;
      }
    }
    sA1[lrow][d] = a1; sA2[lrow][d] = a2;
  }
  __syncthreads();
  float z1[2], z2[2];
  { const float b1 = w1b[d], b2 = w2b[d];
    z1[0] = b1; z1[1] = b1; z2[0] = b2; z2[1] = b2; }
  #pragma unroll 4
  for (int k = 0; k < 128; k++) {
    const float wv1 = w1t[k*128 + d];
    const float wv2 = w2t[k*128 + d];
    #pragma unroll
    for (int q = 0; q < 2; q++) {
      z1[q] += wv1 * sA1[rr*2 + q][k];
      z2[q] += wv2 * sA2[rr*2 + q][k];
    }
  }
  #pragma unroll
  for (int q = 0; q < 2; q++) {
    sC[rr*2 + q][d] = z1[q]; sC[rr*2 + q][128 + d] = z2[q];
  }
  __syncthreads();
  float gl[2];
  { const float bg = gb[d]; gl[0] = bg; gl[1] = bg; }
  #pragma unroll 4
  for (int k = 0; k < 256; k++) {
    const float wv = gwt[k*128 + d];
    #pragma unroll
    for (int q = 0; q < 2; q++)
      gl[q] += wv * sC[rr*2 + q][k];
  }
  const float swd = sw[d];
  #pragma unroll
  for (int q = 0; q < 2; q++) {
    const int row = row0 + rr*2 + q;
    const float gg = 1.f / (1.f + expf(-gl[q]));
    const float zv = gg * z1[q] + (1.f - gg) * z2[q];
    zbuf[(size_t)row*128 + d] = zv;
    sRed[rr*2 + q][d] = zv * swd;
  }
  __syncthreads();
  if (tid < 64) {
    const int r = tid >> 4, j = tid & 15;
    float part = 0.f;
    #pragma unroll
    for (int i = 0; i < 8; i++) part += sRed[r][j*8 + i];
    #pragma unroll
    for (int m = 8; m >= 1; m >>= 1) part += __shfl_xor(part, m, 64);
    if (j == 0) scores[row0 + r] = part + sb[0];
  }
}

// ---------------- top-k (k=112) with jax tie semantics
__global__ __launch_bounds__(256) void k_topk(
    const float* __restrict__ scores, int* __restrict__ sel)
{
  __shared__ float ss[225];
  const int b = blockIdx.x, tid = threadIdx.x;
  if (tid < 112) sel[b*112 + tid] = tid;
  if (tid < 225) ss[tid] = scores[b*225 + tid];
  __syncthreads();
  if (tid < 225) {
    float s = ss[tid];
    int rank = 0;
    for (int j = 0; j < 225; j++) {
      float sj = ss[j];
      rank += (sj > s) || (sj == s && j < tid);
    }
    if (rank < 112) sel[b*112 + rank] = tid;
  }
}

// ---------------- qkv batched: 7 rows per block (256 blocks -> all CUs active)
__global__ __launch_bounds__(256) void k_qkv(
    const float* __restrict__ zbuf, const int* __restrict__ sel,
    const float* __restrict__ iwt, const float* __restrict__ ib,
    float* __restrict__ q, float* __restrict__ k, float* __restrict__ v)
{
  __shared__ float sx[7][128];
  const int s0 = blockIdx.x * 7, b = blockIdx.y;
  const int tid = threadIdx.x;
  const int c = tid & 127, half = tid >> 7;
  const int r0 = half * 4;                 // half0: rows 0..3, half1: rows 4..6
  const int nr = half ? 3 : 4;

  for (int idx = tid; idx < 7*128; idx += 256) {
    const int r = idx >> 7, dd = idx & 127;
    int row = sel[b*112 + s0 + r];
    row = row < 0 ? 0 : (row > 224 ? 224 : row);
    sx[r][dd] = zbuf[((size_t)b*225 + row)*128 + dd];
  }
  __syncthreads();

  float acc[3][4];
  #pragma unroll
  for (int p = 0; p < 3; p++)
    #pragma unroll
    for (int rr = 0; rr < 4; rr++) acc[p][rr] = ib[p*128 + c];
  for (int kk = 0; kk < 128; kk++) {
    float wv[3];
    #pragma unroll
    for (int p = 0; p < 3; p++) wv[p] = iwt[kk*384 + p*128 + c];
    #pragma unroll
    for (int rr = 0; rr < 4; rr++) {
      const int rowi = (r0 + rr < 7) ? (r0 + rr) : 6;   // clamp phantom row
      const float xv = sx[rowi][kk];
      #pragma unroll
      for (int p = 0; p < 3; p++) acc[p][rr] += wv[p] * xv;
    }
  }
  const int h = c >> 5, t = c & 31;
  float* outs[3] = {q, k, v};
  #pragma unroll
  for (int p = 0; p < 3; p++)
    #pragma unroll
    for (int rr = 0; rr < 4; rr++)
      if (rr < nr)
        outs[p][(((size_t)b*4 + h)*112 + s0 + r0 + rr)*32 + t] = acc[p][rr];
}

// ---------------- attention: 512 blocks (8 q-chunks x 4 heads x 16 b), 16 thr/query
__global__ __launch_bounds__(256) void k_attn(
    const float* __restrict__ q, const float* __restrict__ k,
    const float* __restrict__ v, float* __restrict__ o)
{
  __shared__ float sK[112*33], sV[112*33];
  __shared__ float sQ[14*33];
  __shared__ float sP[14][112];
  const int qc = blockIdx.x, h = blockIdx.y, b = blockIdx.z;
  const size_t base = ((size_t)b*4 + h) * 112 * 32;
  const int tid = threadIdx.x;
  for (int i = tid; i < 112*32; i += 256) {
    const int r = i >> 5, c = i & 31;
    sK[r*33 + c] = k[base + i];
    sV[r*33 + c] = v[base + i];
  }
  for (int i = tid; i < 14*32; i += 256) {
    const int r = i >> 5, c = i & 31;
    sQ[r*33 + c] = q[base + (size_t)(qc*14)*32 + i];
  }
  __syncthreads();
  const int qg = tid >> 4, j = tid & 15;
  if (qg < 14) {
    const float scale = 0.17677669529663687f;
    float pv[7];
    float mx = -INFINITY;
    #pragma unroll
    for (int t7 = 0; t7 < 7; t7++) {
      const int kk = j + t7*16;
      float s = 0.f;
      #pragma unroll
      for (int t = 0; t < 32; t++) s += sQ[qg*33 + t] * sK[kk*33 + t];
      pv[t7] = s * scale;
      mx = fmaxf(mx, pv[t7]);
    }
    #pragma unroll
    for (int m = 8; m >= 1; m >>= 1) mx = fmaxf(mx, __shfl_xor(mx, m, 16));
    float lsum = 0.f;
    #pragma unroll
    for (int t7 = 0; t7 < 7; t7++) { pv[t7] = expf(pv[t7] - mx); lsum += pv[t7]; }
    #pragma unroll
    for (int m = 8; m >= 1; m >>= 1) lsum += __shfl_xor(lsum, m, 16);
    const float inv = 1.f / lsum;
    #pragma unroll
    for (int t7 = 0; t7 < 7; t7++) sP[qg][j + t7*16] = pv[t7] * inv;
  }
  __syncthreads();
  if (qg < 14) {
    const int s = qc*14 + qg;
    float o0 = 0.f, o1 = 0.f;
    for (int kk = 0; kk < 112; kk++) {
      const float p = sP[qg][kk];
      o0 += p * sV[kk*33 + j];
      o1 += p * sV[kk*33 + j + 16];
    }
    float* op = o + ((size_t)b*112 + s)*128 + h*32;
    op[j] = o0;
    op[j + 16] = o1;
  }
}

// ---------------- FUSED out-proj + residual + LN1 + FFN + residual + LN2, 7 rows/block
__global__ __launch_bounds__(256) void k_tail(
    const float* __restrict__ o, const float* __restrict__ zbuf,
    const int* __restrict__ sel,
    const float* __restrict__ owt, const float* __restrict__ ob,
    const float* __restrict__ l1g, const float* __restrict__ l1b,
    const float* __restrict__ f1wt, const float* __restrict__ f1b,
    const float* __restrict__ f2wt, const float* __restrict__ f2b,
    const float* __restrict__ l2g, const float* __restrict__ l2b,
    float* __restrict__ h2)
{
  __shared__ float sO[7][128];
  __shared__ float sh[7][128];
  __shared__ float sf[7][512];
  __shared__ float sV[7][128];
  __shared__ float sMean[7], sRstd[7];
  const int s0 = blockIdx.x * 7, b = blockIdx.y;
  const int tid = threadIdx.x;
  const int d = tid & 127, half = tid >> 7;
  const int r0 = half * 4;                 // half0: rows 0..3, half1: rows 4..6
  const int nr = half ? 3 : 4;

  // ---- phase 1: out-proj + residual + LN1 -> sh ----
  for (int idx = tid; idx < 7*128; idx += 256) {
    const int r = idx >> 7, dd = idx & 127;
    sO[r][dd] = o[((size_t)b*112 + s0 + r)*128 + dd];
  }
  __syncthreads();
  {
    float acc[4];
    #pragma unroll
    for (int rr = 0; rr < 4; rr++) acc[rr] = ob[d];
    for (int kk = 0; kk < 128; kk++) {
      const float wv = owt[kk*128 + d];
      #pragma unroll
      for (int rr = 0; rr < 4; rr++) {
        const int rowi = (r0 + rr < 7) ? (r0 + rr) : 6;
        acc[rr] += wv * sO[rowi][kk];
      }
    }
    #pragma unroll
    for (int rr = 0; rr < 4; rr++) {
      if (rr < nr) {
        int row = sel[b*112 + s0 + r0 + rr];
        row = row < 0 ? 0 : (row > 224 ? 224 : row);
        acc[rr] += zbuf[((size_t)b*225 + row)*128 + d];
        sV[r0 + rr][d] = acc[rr];
      }
    }
  }
  __syncthreads();
  {
    const int r = tid >> 4, j = tid & 15;
    if (r < 7) {
      float p1 = 0.f, p2 = 0.f;
      #pragma unroll
      for (int i = 0; i < 8; i++) { float v = sV[r][j*8 + i]; p1 += v; p2 += v*v; }
      #pragma unroll
      for (int m = 8; m >= 1; m >>= 1) {
        p1 += __shfl_xor(p1, m, 64);
        p2 += __shfl_xor(p2, m, 64);
      }
      if (j == 0) {
        const float mean = p1 * (1.f/128.f);
        sMean[r] = mean;
        sRstd[r] = rsqrtf(p2 * (1.f/128.f) - mean*mean + 1e-5f);
      }
    }
  }
  __syncthreads();
  for (int idx = tid; idx < 7*128; idx += 256) {
    const int r = idx >> 7, dd = idx & 127;
    sh[r][dd] = (sV[r][dd] - sMean[r]) * sRstd[r] * l1g[dd] + l1b[dd];
  }
  __syncthreads();

  // ---- phase 2: FFN + residual + LN2 -> h2 ----
  {
    float a0[7], a1[7];
    const float b0 = f1b[tid], b1 = f1b[tid + 256];
    #pragma unroll
    for (int r = 0; r < 7; r++) { a0[r] = b0; a1[r] = b1; }
    for (int kk = 0; kk < 128; kk++) {
      const float w0 = f1wt[kk*512 + tid];
      const float w1 = f1wt[kk*512 + tid + 256];
      #pragma unroll
      for (int r = 0; r < 7; r++) {
        const float xv = sh[r][kk];
        a0[r] += w0 * xv;
        a1[r] += w1 * xv;
      }
    }
    #pragma unroll
    for (int r = 0; r < 7; r++) {
      sf[r][tid]       = fmaxf(a0[r], 0.f);
      sf[r][tid + 256] = fmaxf(a1[r], 0.f);
    }
  }
  __syncthreads();
  {
    float acc[4];
    #pragma unroll
    for (int rr = 0; rr < 4; rr++) acc[rr] = f2b[d];
    for (int kk = 0; kk < 512; kk++) {
      const float wv = f2wt[kk*128 + d];
      #pragma unroll
      for (int rr = 0; rr < 4; rr++) {
        const int rowi = (r0 + rr < 7) ? (r0 + rr) : 6;
        acc[rr] += wv * sf[rowi][kk];
      }
    }
    #pragma unroll
    for (int rr = 0; rr < 4; rr++)
      if (rr < nr)
        sV[r0 + rr][d] = sh[r0 + rr][d] + acc[rr];
  }
  __syncthreads();
  {
    const int r = tid >> 4, j = tid & 15;
    if (r < 7) {
      float p1 = 0.f, p2 = 0.f;
      #pragma unroll
      for (int i = 0; i < 8; i++) { float v = sV[r][j*8 + i]; p1 += v; p2 += v*v; }
      #pragma unroll
      for (int m = 8; m >= 1; m >>= 1) {
        p1 += __shfl_xor(p1, m, 64);
        p2 += __shfl_xor(p2, m, 64);
      }
      if (j == 0) {
        const float mean = p1 * (1.f/128.f);
        sMean[r] = mean;
        sRstd[r] = rsqrtf(p2 * (1.f/128.f) - mean*mean + 1e-5f);
      }
    }
  }
  __syncthreads();
  for (int idx = tid; idx < 7*128; idx += 256) {
    const int r = idx >> 7, dd = idx & 127;
    h2[((size_t)b*112 + s0 + r)*128 + dd] =
        (sV[r][dd] - sMean[r]) * sRstd[r] * l2g[dd] + l2b[dd];
  }
}

// ---------------- rep = sum_s h2 ; classifier -> logits (f32)
__global__ __launch_bounds__(64) void k_cls(
    const float* __restrict__ h2,
    const float* __restrict__ c1w, const float* __restrict__ c1b,
    const float* __restrict__ c2w, const float* __restrict__ c2b,
    float* __restrict__ out)
{
  __shared__ float sr[128], sc[64];
  const int b = blockIdx.x, tid = threadIdx.x;
  float r0 = 0.f, r1 = 0.f;
  for (int s2 = 0; s2 < 112; s2++) {
    const float* row = h2 + ((size_t)b*112 + s2)*128;
    r0 += row[tid];
    r1 += row[tid + 64];
  }
  sr[tid] = r0; sr[tid + 64] = r1;
  __syncthreads();
  float acc = c1b[tid];
  const float* wr = c1w + (size_t)tid * 128;
  for (int kk = 0; kk < 128; kk++) acc += wr[kk] * sr[kk];
  sc[tid] = fmaxf(acc, 0.f);
  __syncthreads();
  if (tid < 2) {
    float l = c2b[tid];
    for (int kk = 0; kk < 64; kk++) l += c2w[tid*64 + kk] * sc[kk];
    out[b*2 + tid] = l;
  }
}

extern "C" void kernel_launch(void* const* d_in, const int* in_sizes, int n_in,
                              void* d_out, int out_size, void* d_ws, size_t ws_size,
                              hipStream_t stream)
{
  const float* x    = (const float*)d_in[0];
  const float* c1w  = (const float*)d_in[1];
  const float* c1b  = (const float*)d_in[2];
  const float* bn1g = (const float*)d_in[3];
  const float* bn1b = (const float*)d_in[4];
  const float* c2w  = (const float*)d_in[5];
  const float* c2b  = (const float*)d_in[6];
  const float* bn2g = (const float*)d_in[7];
  const float* bn2b = (const float*)d_in[8];
  const float* pjw  = (const float*)d_in[9];
  const float* pjb  = (const float*)d_in[10];
  const float* w1w  = (const float*)d_in[11];
  const float* w1b  = (const float*)d_in[12];
  const float* w2w  = (const float*)d_in[13];
  const float* w2b  = (const float*)d_in[14];
  const float* gw   = (const float*)d_in[15];
  const float* gb   = (const float*)d_in[16];
  const float* scw  = (const float*)d_in[17];
  const float* scb  = (const float*)d_in[18];
  const float* ipw  = (const float*)d_in[19];
  const float* ipb  = (const float*)d_in[20];
  const float* opw  = (const float*)d_in[21];
  const float* opb  = (const float*)d_in[22];
  const float* f1w  = (const float*)d_in[23];
  const float* f1b  = (const float*)d_in[24];
  const float* f2w  = (const float*)d_in[25];
  const float* f2b  = (const float*)d_in[26];
  const float* l1g  = (const float*)d_in[27];
  const float* l1b  = (const float*)d_in[28];
  const float* l2g  = (const float*)d_in[29];
  const float* l2b  = (const float*)d_in[30];
  const float* cl1w = (const float*)d_in[31];
  const float* cl1b = (const float*)d_in[32];
  const float* cl2w = (const float*)d_in[33];
  const float* cl2b = (const float*)d_in[34];

  // ---- bump allocator over d_ws (256-B aligned) ----
  char* p = (char*)d_ws;
  auto alloc = [&](size_t n) { char* r = p; p += (n + 255) & ~(size_t)255; return r; };
  u64*   mask2  = (u64*)  alloc(900    * sizeof(u64));
  int*   nbr1   = (int*)  alloc(1800   * sizeof(int));
  int*   sel    = (int*)  alloc(1792   * sizeof(int));
  float* scores = (float*)alloc(3600   * sizeof(float));
  u16*   pwh    = (u16*)  alloc(524288 * sizeof(u16));
  u16*   pwl    = (u16*)  alloc(524288 * sizeof(u16));
  u16*   wc2h   = (u16*)  alloc(36864  * sizeof(u16));
  u16*   wc2l   = (u16*)  alloc(36864  * sizeof(u16));
  u16*   wc1h   = (u16*)  alloc(2048   * sizeof(u16));
  u16*   wc1l   = (u16*)  alloc(2048   * sizeof(u16));
  float* iwt    = (float*)alloc(49152  * sizeof(float));
  float* owt    = (float*)alloc(16384  * sizeof(float));
  float* f1wt   = (float*)alloc(65536  * sizeof(float));
  float* f2wt   = (float*)alloc(65536  * sizeof(float));
  float* w1t    = (float*)alloc(16384  * sizeof(float));
  float* w2t    = (float*)alloc(16384  * sizeof(float));
  float* gwt    = (float*)alloc(32768  * sizeof(float));
  float* partial= (float*)alloc(8ull*16*225*128 * sizeof(float));  // 14.7 MB split-K=8
  float* zbuf   = (float*)alloc(460800 * sizeof(float));
  float* nodes  = (float*)alloc(460800 * sizeof(float));
  const size_t fixed_bytes = (size_t)(p - (char*)d_ws);

  const size_t qkv_bytes = 3ull * 229376ull * sizeof(float);
  const size_t per_batch = 64ull*128*128*2 + 64ull*64*64*2;   // 2,621,440 B
  int BC = 16;
  size_t s3 = 0;
  for (;; BC >>= 1) {
    s3 = (size_t)BC * per_batch; if (s3 < qkv_bytes) s3 = qkv_bytes;
    if (fixed_bytes + s3 + 65536 <= ws_size) break;
    if (BC == 1) { return; }
  }
  char* S3 = alloc(s3);

  u16*   feat1 = (u16*)S3;                              // NHWC (BC,128,128,64)
  u16*   feat2 = (u16*)(S3 + (size_t)BC * 2097152ull);  // NCHW (BC,64,64,64)
  float* qb    = (float*)S3;
  float* kb    = qb + 229376;
  float* vb    = kb + 229376;
  float* obuf  = nodes;                                 // nodes dead after k_gz2
  float* hbuf  = nodes + 229376;                        // h2

  k_prep<<<1913, 256, 0, stream>>>(pjw, pwh, pwl, c2w, bn2g, wc2h, wc2l,
                                   c1w, bn1g, wc1h, wc1l,
                                   ipw, iwt, opw, owt, f1w, f1wt, f2w, f2wt,
                                   w1w, w1t, w2w, w2t, gw, gwt, nbr1);
  k_adj2<<<1, 256, 0, stream>>>(nbr1, mask2);

  for (int b0 = 0; b0 < 16; b0 += BC) {
    k_conv1m<<<dim3(16,16,BC), 256, 0, stream>>>(x, wc1h, wc1l, c1b, bn1g, bn1b, feat1, b0);
    k_conv2m<<<dim3(4,8,BC), 256, 0, stream>>>(feat1, wc2h, wc2l, c2b, bn2g, bn2b, feat2);
    k_projm <<<dim3(8,8,BC), 256, 0, stream>>>(feat2, pwh, pwl, partial, b0);
    k_projr <<<dim3(225,BC), 128, 0, stream>>>(partial, pjb, nodes, b0);
  }

  k_gz2  <<<900, 256, 0, stream>>>(nodes, nbr1, mask2, w1t, w1b, w2t, w2b,
                                   gwt, gb, scw, scb, zbuf, scores);
  k_topk <<<16, 256, 0, stream>>>(scores, sel);
  k_qkv  <<<dim3(16,16), 256, 0, stream>>>(zbuf, sel, iwt, ipb, qb, kb, vb);
  k_attn <<<dim3(8,4,16), 256, 0, stream>>>(qb, kb, vb, obuf);
  k_tail <<<dim3(16,16), 256, 0, stream>>>(obuf, zbuf, sel, owt, opb, l1g, l1b,
                                           f1wt, f1b, f2wt, f2b, l2g, l2b, hbuf);
  k_cls  <<<16, 64, 0, stream>>>(hbuf, cl1w, cl1b, cl2w, cl2b, (float*)d_out);
}

// Round 26
// 256.772 us; speedup vs baseline: 1.1346x; 1.1346x over previous
//
#include <hip/hip_runtime.h>
#include <hip/hip_bf16.h>
#include <math.h>

typedef unsigned short u16;
typedef unsigned int   u32;
typedef unsigned long long u64;
typedef __attribute__((ext_vector_type(8))) short short8v;
typedef __attribute__((ext_vector_type(4))) float f32x4;

__device__ __forceinline__ float bf2f(u16 u) {
  union { u32 i; float f; } v; v.i = ((u32)u) << 16; return v.f;
}
__device__ __forceinline__ u16 f2bf(float f) {  // round-to-nearest-even
  union { float f; u32 i; } v; v.f = f;
  u32 r = (v.i + 0x7FFFu + ((v.i >> 16) & 1u)) >> 16;
  return (u16)r;
}

// ---------------- conv1 + bn1 + relu + maxpool2 via MFMA im2col (K=32, hi/lo input split)
// T2 XOR chunk swizzle on sA*/sB* (write chunk = logical ^ (row&3); read likewise)
__global__ __launch_bounds__(256, 2) void k_conv1m(
    const float* __restrict__ x,
    const u16* __restrict__ wh, const u16* __restrict__ wl,
    const float* __restrict__ cb, const float* __restrict__ g, const float* __restrict__ bb,
    u16* __restrict__ feat1, int b0)
{
  __shared__ __align__(16) u16 sInH[3*18*18], sInL[3*18*18];
  __shared__ __align__(16) u16 sAh[256*40], sAl[256*40];
  __shared__ __align__(16) u16 sBh[64*40],  sBl[64*40];
  __shared__ float sBias[64];
  const int tx = blockIdx.x, ty = blockIdx.y, bl = blockIdx.z;
  const int b = b0 + bl;
  const int y0 = ty*16, x0 = tx*16;
  const int tid = threadIdx.x;
  const int w = tid >> 6, l = tid & 63, lr = l & 15, lk = l >> 4;

  if (tid < 64) {
    float sc = g[tid] * rsqrtf(1.0f + 1e-5f);
    sBias[tid] = cb[tid] * sc + bb[tid];
  }
  {
    const int oc = tid >> 2, seg = tid & 3;
    const int ps = seg ^ (oc & 3);           // swizzled chunk
    *reinterpret_cast<uint4*>(&sBh[oc*40 + ps*8]) =
        *reinterpret_cast<const uint4*>(wh + oc*32 + seg*8);
    *reinterpret_cast<uint4*>(&sBl[oc*40 + ps*8]) =
        *reinterpret_cast<const uint4*>(wl + oc*32 + seg*8);
  }
  for (int i = tid; i < 3*18*18; i += 256) {
    const int c = i / 324, r = (i / 18) % 18, q = i % 18;
    const int yy = y0 - 1 + r, xx = x0 - 1 + q;
    float v = 0.f;
    if (yy >= 0 && yy < 256 && xx >= 0 && xx < 256)
      v = x[(((size_t)b*3 + c)*256 + yy)*256 + xx];
    const u16 h = f2bf(v);
    sInH[i] = h;
    sInL[i] = f2bf(v - bf2f(h));
  }
  __syncthreads();
  {
    const int py = tid >> 4, px = tid & 15;
    u32 hw[16], lw[16];
    #pragma unroll
    for (int i = 0; i < 16; i++) { hw[i] = 0u; lw[i] = 0u; }
    #pragma unroll
    for (int c = 0; c < 3; c++)
      #pragma unroll
      for (int ky = 0; ky < 3; ky++)
        #pragma unroll
        for (int kx = 0; kx < 3; kx++) {
          const int k = c*9 + ky*3 + kx;
          const int src = (c*18 + py + ky)*18 + px + kx;
          hw[k >> 1] |= ((u32)sInH[src]) << ((k & 1)*16);
          lw[k >> 1] |= ((u32)sInL[src]) << ((k & 1)*16);
        }
    #pragma unroll
    for (int s = 0; s < 4; s++) {
      const int ps = s ^ (tid & 3);          // swizzled chunk
      uint4 vh, vl;
      vh.x = hw[s*4+0]; vh.y = hw[s*4+1]; vh.z = hw[s*4+2]; vh.w = hw[s*4+3];
      vl.x = lw[s*4+0]; vl.y = lw[s*4+1]; vl.z = lw[s*4+2]; vl.w = lw[s*4+3];
      *reinterpret_cast<uint4*>(&sAh[tid*40 + ps*8]) = vh;
      *reinterpret_cast<uint4*>(&sAl[tid*40 + ps*8]) = vl;
    }
  }
  __syncthreads();
  f32x4 acc[4][4];
  #pragma unroll
  for (int j = 0; j < 4; j++)
    #pragma unroll
    for (int ct = 0; ct < 4; ct++)
      acc[j][ct] = (f32x4){0.f,0.f,0.f,0.f};
  const int lkA = lk ^ (lr & 3);             // swizzled read chunk (pix&3 == lr&3)
  #pragma unroll
  for (int j = 0; j < 4; j++) {
    const int mt = w*4 + j;
    const short8v ah = *reinterpret_cast<const short8v*>(&sAh[(mt*16 + lr)*40 + lkA*8]);
    const short8v al = *reinterpret_cast<const short8v*>(&sAl[(mt*16 + lr)*40 + lkA*8]);
    #pragma unroll
    for (int ct = 0; ct < 4; ct++) {
      const short8v bh = *reinterpret_cast<const short8v*>(&sBh[(ct*16 + lr)*40 + lkA*8]);
      const short8v bv = *reinterpret_cast<const short8v*>(&sBl[(ct*16 + lr)*40 + lkA*8]);
      acc[j][ct] = __builtin_amdgcn_mfma_f32_16x16x32_bf16(ah, bh, acc[j][ct], 0, 0, 0);
      acc[j][ct] = __builtin_amdgcn_mfma_f32_16x16x32_bf16(ah, bv, acc[j][ct], 0, 0, 0);
      acc[j][ct] = __builtin_amdgcn_mfma_f32_16x16x32_bf16(al, bh, acc[j][ct], 0, 0, 0);
    }
  }
  #pragma unroll
  for (int j = 0; j < 2; j++) {
    const int jA = 2*j, jB = 2*j + 1;
    const int oy = ty*8 + w*2 + j;
    #pragma unroll
    for (int xh = 0; xh < 2; xh++) {
      const int ox = tx*8 + lk*2 + xh;
      #pragma unroll
      for (int ct = 0; ct < 4; ct++) {
        const int oc = ct*16 + lr;
        float m = fmaxf(fmaxf(acc[jA][ct][2*xh], acc[jA][ct][2*xh+1]),
                        fmaxf(acc[jB][ct][2*xh], acc[jB][ct][2*xh+1]));
        m = fmaxf(m + sBias[oc], 0.f);
        feat1[(((size_t)bl*128 + oy)*128 + ox)*64 + oc] = f2bf(m);
      }
    }
  }
}

// ---------------- conv2 + bn2 + relu + maxpool2 via MFMA implicit GEMM (B dbuf, T2 swizzle)
__global__ __launch_bounds__(256, 2) void k_conv2m(
    const u16* __restrict__ feat1,
    const u16* __restrict__ wh, const u16* __restrict__ wl,
    const float* __restrict__ cb, const float* __restrict__ g, const float* __restrict__ bb,
    u16* __restrict__ feat2)
{
  __shared__ __align__(16) u16 sA[18*34*40];
  __shared__ __align__(16) u16 sBh[2][64*40], sBl[2][64*40];
  __shared__ float sBias[64];
  const int tx = blockIdx.x, ty = blockIdx.y, bl = blockIdx.z;
  const int y0 = ty*16, x0 = tx*32;
  const int tid = threadIdx.x;
  const int w = tid >> 6, l = tid & 63;
  const int lr = l & 15, lk = l >> 4;

  if (tid < 64) {
    float sc = g[tid] * rsqrtf(1.0f + 1e-5f);
    sBias[tid] = cb[tid] * sc + bb[tid];
  }

  f32x4 acc[8][4];
  #pragma unroll
  for (int j = 0; j < 8; j++)
    #pragma unroll
    for (int ct = 0; ct < 4; ct++)
      acc[j][ct] = (f32x4){0.f,0.f,0.f,0.f};

  const int ocB = tid >> 2;
  const int psB = (tid & 3) ^ (ocB & 3);     // swizzled B chunk
  uint4 rBh, rBl;
  auto ldB = [&](int chunk, int kk) {
    const size_t src = (size_t)(kk*2 + chunk)*2048 + tid*8;
    rBh = *reinterpret_cast<const uint4*>(wh + src);
    rBl = *reinterpret_cast<const uint4*>(wl + src);
  };
  auto stB = [&](int buf) {
    *reinterpret_cast<uint4*>(&sBh[buf][ocB*40 + psB*8]) = rBh;
    *reinterpret_cast<uint4*>(&sBl[buf][ocB*40 + psB*8]) = rBl;
  };

  const int lkB = lk ^ (lr & 3);             // swizzled B read chunk
  for (int chunk = 0; chunk < 2; chunk++) {
    __syncthreads();
    ldB(chunk, 0);
    for (int idx = tid; idx < 612*4; idx += 256) {
      const int pix = idx >> 2, seg = idx & 3;
      const int r = pix / 34, cc = pix % 34;
      const int yy = y0 - 1 + r, xx = x0 - 1 + cc;
      uint4 v = {0u,0u,0u,0u};
      if (yy >= 0 && yy < 128 && xx >= 0 && xx < 128)
        v = *reinterpret_cast<const uint4*>(
              feat1 + (((size_t)bl*128 + yy)*128 + xx)*64 + chunk*32 + seg*8);
      const int ps = seg ^ (pix & 3);        // swizzled A chunk
      *reinterpret_cast<uint4*>(&sA[(size_t)pix*40 + ps*8]) = v;
    }
    stB(0);
    __syncthreads();
    int cur = 0;
    for (int kk = 0; kk < 9; kk++) {
      if (kk + 1 < 9) ldB(chunk, kk + 1);
      const int ky = kk / 3, kx = kk % 3;
      short8v a[8];
      #pragma unroll
      for (int j = 0; j < 8; j++) {
        const int m = w*8 + j;
        const int r = (m >> 1) + ky;
        const int cc = (m & 1)*16 + lr + kx;
        const int pixR = r*34 + cc;
        const int lkR = lk ^ (pixR & 3);     // swizzled A read chunk
        a[j] = *reinterpret_cast<const short8v*>(&sA[(size_t)pixR*40 + lkR*8]);
      }
      #pragma unroll
      for (int ct = 0; ct < 4; ct++) {
        const short8v bh = *reinterpret_cast<const short8v*>(&sBh[cur][(ct*16 + lr)*40 + lkB*8]);
        const short8v bv = *reinterpret_cast<const short8v*>(&sBl[cur][(ct*16 + lr)*40 + lkB*8]);
        #pragma unroll
        for (int j = 0; j < 8; j++) {
          acc[j][ct] = __builtin_amdgcn_mfma_f32_16x16x32_bf16(a[j], bh, acc[j][ct], 0, 0, 0);
          acc[j][ct] = __builtin_amdgcn_mfma_f32_16x16x32_bf16(a[j], bv, acc[j][ct], 0, 0, 0);
        }
      }
      if (kk + 1 < 9) {
        stB(cur ^ 1);
        __syncthreads();
        cur ^= 1;
      }
    }
  }
  #pragma unroll
  for (int u = 0; u < 2; u++) {
    #pragma unroll
    for (int xh = 0; xh < 2; xh++) {
      const int jA = 4*u + xh, jB = 4*u + 2 + xh;
      #pragma unroll
      for (int ct = 0; ct < 4; ct++) {
        const int oc = ct*16 + lr;
        const float bias = sBias[oc];
        const float v0 = fmaxf(fmaxf(acc[jA][ct][0], acc[jA][ct][1]),
                               fmaxf(acc[jB][ct][0], acc[jB][ct][1]));
        const float v1 = fmaxf(fmaxf(acc[jA][ct][2], acc[jA][ct][3]),
                               fmaxf(acc[jB][ct][2], acc[jB][ct][3]));
        const u16 b0v = f2bf(fmaxf(v0 + bias, 0.f));
        const u16 b1v = f2bf(fmaxf(v1 + bias, 0.f));
        const int py = ty*8 + 2*w + u;
        const int px = tx*16 + xh*8 + lk*2;
        u32 pk = (u32)b0v | ((u32)b1v << 16);
        *reinterpret_cast<u32*>(&feat2[(((size_t)bl*64 + oc)*64 + py)*64 + px]) = pk;
      }
    }
  }
}

// ---------------- adjacency phase 2: mask2 = rows of (adj@adj>0) minus diagonal
__global__ __launch_bounds__(256) void k_adj2(
    const int* __restrict__ nbr1, u64* __restrict__ mask2)
{
  const int i = threadIdx.x;
  if (i >= 225) return;
  u64 m0=0, m1=0, m2=0, m3=0;
  #pragma unroll
  for (int t = 0; t < 8; t++) {
    const int tt = nbr1[i*8 + t];
    #pragma unroll
    for (int u = 0; u < 8; u++) {
      const int j = nbr1[tt*8 + u];
      const u64 bset = 1ull << (j & 63);
      const int wd = j >> 6;
      m0 |= (wd == 0) ? bset : 0ull;
      m1 |= (wd == 1) ? bset : 0ull;
      m2 |= (wd == 2) ? bset : 0ull;
      m3 |= (wd == 3) ? bset : 0ull;
    }
  }
  {
    const u64 bc = ~(1ull << (i & 63));
    const int wd = i >> 6;
    if (wd == 0) m0 &= bc; else if (wd == 1) m1 &= bc;
    else if (wd == 2) m2 &= bc; else m3 &= bc;
  }
  mask2[i*4+0] = m0; mask2[i*4+1] = m1; mask2[i*4+2] = m2; mask2[i*4+3] = m3;
}

// ---------------- fused weight prep + adjacency 8-NN (blocks >= 1688)
__global__ __launch_bounds__(256) void k_prep(
    const float* __restrict__ pjw, u16* __restrict__ pwh, u16* __restrict__ pwl,
    const float* __restrict__ c2w, const float* __restrict__ bn2g,
    u16* __restrict__ wc2h, u16* __restrict__ wc2l,
    const float* __restrict__ c1w, const float* __restrict__ bn1g,
    u16* __restrict__ wc1h, u16* __restrict__ wc1l,
    const float* __restrict__ ipw, float* __restrict__ iwt,
    const float* __restrict__ opw, float* __restrict__ owt,
    const float* __restrict__ f1w, float* __restrict__ f1wt,
    const float* __restrict__ f2w, float* __restrict__ f2wt,
    const float* __restrict__ w1w, float* __restrict__ w1t,
    const float* __restrict__ w2w, float* __restrict__ w2t,
    const float* __restrict__ gw,  float* __restrict__ gwt,
    int* __restrict__ nbr1)
{
  __shared__ int skey[256];
  __shared__ int sred[256];
  const int blk = blockIdx.x, tid = threadIdx.x;
  if (blk < 512) {
    const int i = (blk*256 + tid) * 4;
    float4 v = *reinterpret_cast<const float4*>(pjw + i);
    float e[4] = {v.x, v.y, v.z, v.w};
    ushort4 h, l;
    u16* hp = &h.x; u16* lp = &l.x;
    #pragma unroll
    for (int j = 0; j < 4; j++) {
      u16 hb = f2bf(e[j]);
      hp[j] = hb;
      lp[j] = f2bf(e[j] - bf2f(hb));
    }
    *reinterpret_cast<ushort4*>(pwh + i) = h;
    *reinterpret_cast<ushort4*>(pwl + i) = l;
  } else if (blk < 656) {
    const int d = (blk - 512)*256 + tid;
    if (d < 36864) {
      const int icL = d & 31, oc = (d >> 5) & 63, chunk = (d >> 11) & 1, kk = d >> 12;
      const float sc = bn2g[oc] * rsqrtf(1.0f + 1e-5f);
      const float val = c2w[((size_t)oc*64 + chunk*32 + icL)*9 + kk] * sc;
      const u16 hb = f2bf(val);
      wc2h[d] = hb;
      wc2l[d] = f2bf(val - bf2f(hb));
    }
  } else if (blk < 664) {
    const int d = (blk - 656)*256 + tid;
    if (d < 2048) {
      const int k = d & 31, oc = d >> 5;
      float val = 0.f;
      if (k < 27) val = c1w[oc*27 + k] * (bn1g[oc] * rsqrtf(1.0f + 1e-5f));
      const u16 hb = f2bf(val);
      wc1h[d] = hb;
      wc1l[d] = f2bf(val - bf2f(hb));
    }
  } else if (blk < 1688) {
    const float* src; float* dst; int O, K, base;
    if      (blk <  856) { src = ipw; dst = iwt;  O = 384; K = 128; base = 664;  }
    else if (blk <  920) { src = opw; dst = owt;  O = 128; K = 128; base = 856;  }
    else if (blk < 1176) { src = f1w; dst = f1wt; O = 512; K = 128; base = 920;  }
    else if (blk < 1432) { src = f2w; dst = f2wt; O = 128; K = 512; base = 1176; }
    else if (blk < 1496) { src = w1w; dst = w1t;  O = 128; K = 128; base = 1432; }
    else if (blk < 1560) { src = w2w; dst = w2t;  O = 128; K = 128; base = 1496; }
    else                 { src = gw;  dst = gwt;  O = 128; K = 256; base = 1560; }
    const int idx = (blk - base)*256 + tid;
    if (idx < O * K) {
      const int o = idx / K, k = idx % K;
      dst[(size_t)k * O + o] = src[idx];
    }
  } else {
    const int i = blk - 1688;
    int key = 0x7FFFFFFF;
    if (tid < 225 && tid != i) {
      const int di = i/15 - tid/15, dj = i%15 - tid%15;
      key = (di*di + dj*dj)*256 + tid;
    }
    skey[tid] = key;
    __syncthreads();
    for (int t = 0; t < 8; t++) {
      sred[tid] = skey[tid];
      __syncthreads();
      #pragma unroll
      for (int st = 128; st > 0; st >>= 1) {
        if (tid < st) sred[tid] = min(sred[tid], sred[tid+st]);
        __syncthreads();
      }
      const int wj = sred[0] & 255;
      if (tid == 0) nbr1[i*8 + t] = wj;
      __syncthreads();
      if (tid == wj) skey[tid] = 0x7FFFFFFF;
      __syncthreads();
    }
  }
}

// ---------------- patch-projection MFMA GEMM, split-K=8, A direct-load w/ 1-step register
// prefetch, B dbuf + T2 swizzle (round-24 tile shape: 64 rows, grid 4x8x16)
__global__ __launch_bounds__(256, 2) void k_projm(
    const u16* __restrict__ feat2,
    const u16* __restrict__ pwh, const u16* __restrict__ pwl,
    float* __restrict__ partial, int b0)
{
  __shared__ __align__(16) u16 sBh[2][128*40];
  __shared__ __align__(16) u16 sBl[2][128*40];
  const int cx = blockIdx.x, kc = blockIdx.y, bl = blockIdx.z;
  const int b  = b0 + bl;
  const int n0 = cx * 64;
  const int rows = (225 - n0) < 64 ? (225 - n0) : 64;
  const int tid = threadIdx.x;
  const int w = tid >> 6, l = tid & 63;
  const int lr = l & 15, lk = l >> 4;

  f32x4 acc[8];
  #pragma unroll
  for (int i = 0; i < 8; i++) acc[i] = (f32x4){0.f, 0.f, 0.f, 0.f};

  int an = n0 + w*16 + lr;
  if (an > 224) an = 224;
  const int aph = an / 15, apw = an % 15;
  const int kbeg = kc * 512, kend = kbeg + 512;

  uint4 rBh[2], rBl[2];
  auto ldB = [&](int k0) {
    #pragma unroll
    for (int p = 0; p < 2; p++) {
      const int idx = p*256 + tid;
      const int col = idx >> 2, seg = idx & 3;
      const size_t off = (size_t)col*4096 + k0 + seg*8;
      rBh[p] = *reinterpret_cast<const uint4*>(pwh + off);
      rBl[p] = *reinterpret_cast<const uint4*>(pwl + off);
    }
  };
  auto stB = [&](int buf) {
    #pragma unroll
    for (int p = 0; p < 2; p++) {
      const int idx = p*256 + tid;
      const int col = idx >> 2, seg = idx & 3;
      const int ps = seg ^ (col & 3);        // swizzled chunk
      *reinterpret_cast<uint4*>(&sBh[buf][col*40 + ps*8]) = rBh[p];
      *reinterpret_cast<uint4*>(&sBl[buf][col*40 + ps*8]) = rBl[p];
    }
  };
  auto ldA = [&](int k0, uint2& a0, uint2& a1) {
    const int c = k0 >> 6;
    const int i = ((k0 & 32) >> 3) + lk;
    const u16* ap = feat2 + (((size_t)bl*64 + c)*64 + aph*4 + i)*64 + apw*4;
    a0 = *reinterpret_cast<const uint2*>(ap);
    a1 = *reinterpret_cast<const uint2*>(ap + 4);
  };

  const int lkB = lk ^ (lr & 3);             // swizzled read chunk
  uint2 a0c, a1c, a0n, a1n;
  ldB(kbeg);
  ldA(kbeg, a0c, a1c);
  stB(0);
  __syncthreads();
  int cur = 0;
  for (int k0 = kbeg; k0 < kend; k0 += 32) {
    const bool more = (k0 + 32 < kend);
    if (more) { ldB(k0 + 32); ldA(k0 + 32, a0n, a1n); }
    union { short8v v; uint2 u[2]; } a;
    a.u[0] = a0c; a.u[1] = a1c;
    #pragma unroll
    for (int ct = 0; ct < 8; ct++) {
      const short8v bh = *reinterpret_cast<const short8v*>(&sBh[cur][(ct*16 + lr)*40 + lkB*8]);
      const short8v bv = *reinterpret_cast<const short8v*>(&sBl[cur][(ct*16 + lr)*40 + lkB*8]);
      acc[ct] = __builtin_amdgcn_mfma_f32_16x16x32_bf16(a.v, bh, acc[ct], 0, 0, 0);
      acc[ct] = __builtin_amdgcn_mfma_f32_16x16x32_bf16(a.v, bv, acc[ct], 0, 0, 0);
    }
    if (more) {
      stB(cur ^ 1);
      __syncthreads();
      cur ^= 1;
      a0c = a0n; a1c = a1n;
    }
  }
  #pragma unroll
  for (int ct = 0; ct < 8; ct++) {
    const int col = ct*16 + lr;
    #pragma unroll
    for (int v = 0; v < 4; v++) {
      const int r = w*16 + lk*4 + v;
      if (r < rows)
        partial[(((size_t)kc*16 + b)*225 + n0 + r)*128 + col] = acc[ct][v];
    }
  }
}

// ---------------- reduce split-K partials + bias -> nodes
__global__ __launch_bounds__(128) void k_projr(
    const float* __restrict__ partial, const float* __restrict__ pb,
    float* __restrict__ nodes, int b0)
{
  const int n = blockIdx.x, bl = blockIdx.y;
  const int b = b0 + bl;
  const int d = threadIdx.x;
  float s = pb[d];
  #pragma unroll
  for (int kc = 0; kc < 8; kc++)
    s += partial[(((size_t)kc*16 + b)*225 + n)*128 + d];
  nodes[((size_t)b*225 + n)*128 + d] = s;
}

// ---------------- FUSED gather + z1/z2/gate/score: 4 rows per block (900 blocks)
__global__ __launch_bounds__(256) void k_gz2(
    const float* __restrict__ nodes, const int* __restrict__ nbr1,
    const u64* __restrict__ mask2,
    const float* __restrict__ w1t, const float* __restrict__ w1b,
    const float* __restrict__ w2t, const float* __restrict__ w2b,
    const float* __restrict__ gwt, const float* __restrict__ gb,
    const float* __restrict__ sw, const float* __restrict__ sb,
    float* __restrict__ zbuf, float* __restrict__ scores)
{
  __shared__ float sA1[4][128], sA2[4][128], sC[4][256], sRed[4][128];
  const int row0 = blockIdx.x * 4;
  const int tid = threadIdx.x;
  const int d = tid & 127, rr = tid >> 7;
  #pragma unroll
  for (int q = 0; q < 2; q++) {
    const int lrow = rr*2 + q;
    const int row = row0 + lrow;
    const int b = row / 225, n = row % 225;
    const float* nb = nodes + (size_t)b * 225 * 128;
    float a1 = 0.f;
    #pragma unroll
    for (int t = 0; t < 8; t++) a1 += nb[(size_t)nbr1[n*8+t]*128 + d];
    float a2 = 0.f;
    for (int wd = 0; wd < 4; wd++) {
      u64 m = mask2[n*4 + wd];
      while (m) {
        int j = wd*64 + __builtin_ctzll(m);
        a2 += nb[(size_t)j*128 + d];
        m &= m - 1;
      }
    }
    sA1[lrow][d] = a1; sA2[lrow][d] = a2;
  }
  __syncthreads();
  float z1[2], z2[2];
  { const float b1 = w1b[d], b2 = w2b[d];
    z1[0] = b1; z1[1] = b1; z2[0] = b2; z2[1] = b2; }
  #pragma unroll 4
  for (int k = 0; k < 128; k++) {
    const float wv1 = w1t[k*128 + d];
    const float wv2 = w2t[k*128 + d];
    #pragma unroll
    for (int q = 0; q < 2; q++) {
      z1[q] += wv1 * sA1[rr*2 + q][k];
      z2[q] += wv2 * sA2[rr*2 + q][k];
    }
  }
  #pragma unroll
  for (int q = 0; q < 2; q++) {
    sC[rr*2 + q][d] = z1[q]; sC[rr*2 + q][128 + d] = z2[q];
  }
  __syncthreads();
  float gl[2];
  { const float bg = gb[d]; gl[0] = bg; gl[1] = bg; }
  #pragma unroll 4
  for (int k = 0; k < 256; k++) {
    const float wv = gwt[k*128 + d];
    #pragma unroll
    for (int q = 0; q < 2; q++)
      gl[q] += wv * sC[rr*2 + q][k];
  }
  const float swd = sw[d];
  #pragma unroll
  for (int q = 0; q < 2; q++) {
    const int row = row0 + rr*2 + q;
    const float gg = 1.f / (1.f + expf(-gl[q]));
    const float zv = gg * z1[q] + (1.f - gg) * z2[q];
    zbuf[(size_t)row*128 + d] = zv;
    sRed[rr*2 + q][d] = zv * swd;
  }
  __syncthreads();
  if (tid < 64) {
    const int r = tid >> 4, j = tid & 15;
    float part = 0.f;
    #pragma unroll
    for (int i = 0; i < 8; i++) part += sRed[r][j*8 + i];
    #pragma unroll
    for (int m = 8; m >= 1; m >>= 1) part += __shfl_xor(part, m, 64);
    if (j == 0) scores[row0 + r] = part + sb[0];
  }
}

// ---------------- top-k (k=112) with jax tie semantics
__global__ __launch_bounds__(256) void k_topk(
    const float* __restrict__ scores, int* __restrict__ sel)
{
  __shared__ float ss[225];
  const int b = blockIdx.x, tid = threadIdx.x;
  if (tid < 112) sel[b*112 + tid] = tid;
  if (tid < 225) ss[tid] = scores[b*225 + tid];
  __syncthreads();
  if (tid < 225) {
    float s = ss[tid];
    int rank = 0;
    for (int j = 0; j < 225; j++) {
      float sj = ss[j];
      rank += (sj > s) || (sj == s && j < tid);
    }
    if (rank < 112) sel[b*112 + rank] = tid;
  }
}

// ---------------- qkv batched: 7 rows per block (256 blocks -> all CUs active)
__global__ __launch_bounds__(256) void k_qkv(
    const float* __restrict__ zbuf, const int* __restrict__ sel,
    const float* __restrict__ iwt, const float* __restrict__ ib,
    float* __restrict__ q, float* __restrict__ k, float* __restrict__ v)
{
  __shared__ float sx[7][128];
  const int s0 = blockIdx.x * 7, b = blockIdx.y;
  const int tid = threadIdx.x;
  const int c = tid & 127, half = tid >> 7;
  const int r0 = half * 4;                 // half0: rows 0..3, half1: rows 4..6
  const int nr = half ? 3 : 4;

  for (int idx = tid; idx < 7*128; idx += 256) {
    const int r = idx >> 7, dd = idx & 127;
    int row = sel[b*112 + s0 + r];
    row = row < 0 ? 0 : (row > 224 ? 224 : row);
    sx[r][dd] = zbuf[((size_t)b*225 + row)*128 + dd];
  }
  __syncthreads();

  float acc[3][4];
  #pragma unroll
  for (int p = 0; p < 3; p++)
    #pragma unroll
    for (int rr = 0; rr < 4; rr++) acc[p][rr] = ib[p*128 + c];
  for (int kk = 0; kk < 128; kk++) {
    float wv[3];
    #pragma unroll
    for (int p = 0; p < 3; p++) wv[p] = iwt[kk*384 + p*128 + c];
    #pragma unroll
    for (int rr = 0; rr < 4; rr++) {
      const int rowi = (r0 + rr < 7) ? (r0 + rr) : 6;   // clamp phantom row
      const float xv = sx[rowi][kk];
      #pragma unroll
      for (int p = 0; p < 3; p++) acc[p][rr] += wv[p] * xv;
    }
  }
  const int h = c >> 5, t = c & 31;
  float* outs[3] = {q, k, v};
  #pragma unroll
  for (int p = 0; p < 3; p++)
    #pragma unroll
    for (int rr = 0; rr < 4; rr++)
      if (rr < nr)
        outs[p][(((size_t)b*4 + h)*112 + s0 + r0 + rr)*32 + t] = acc[p][rr];
}

// ---------------- attention: 512 blocks (8 q-chunks x 4 heads x 16 b), 16 thr/query
__global__ __launch_bounds__(256) void k_attn(
    const float* __restrict__ q, const float* __restrict__ k,
    const float* __restrict__ v, float* __restrict__ o)
{
  __shared__ float sK[112*33], sV[112*33];
  __shared__ float sQ[14*33];
  __shared__ float sP[14][112];
  const int qc = blockIdx.x, h = blockIdx.y, b = blockIdx.z;
  const size_t base = ((size_t)b*4 + h) * 112 * 32;
  const int tid = threadIdx.x;
  for (int i = tid; i < 112*32; i += 256) {
    const int r = i >> 5, c = i & 31;
    sK[r*33 + c] = k[base + i];
    sV[r*33 + c] = v[base + i];
  }
  for (int i = tid; i < 14*32; i += 256) {
    const int r = i >> 5, c = i & 31;
    sQ[r*33 + c] = q[base + (size_t)(qc*14)*32 + i];
  }
  __syncthreads();
  const int qg = tid >> 4, j = tid & 15;
  if (qg < 14) {
    const float scale = 0.17677669529663687f;
    float pv[7];
    float mx = -INFINITY;
    #pragma unroll
    for (int t7 = 0; t7 < 7; t7++) {
      const int kk = j + t7*16;
      float s = 0.f;
      #pragma unroll
      for (int t = 0; t < 32; t++) s += sQ[qg*33 + t] * sK[kk*33 + t];
      pv[t7] = s * scale;
      mx = fmaxf(mx, pv[t7]);
    }
    #pragma unroll
    for (int m = 8; m >= 1; m >>= 1) mx = fmaxf(mx, __shfl_xor(mx, m, 16));
    float lsum = 0.f;
    #pragma unroll
    for (int t7 = 0; t7 < 7; t7++) { pv[t7] = expf(pv[t7] - mx); lsum += pv[t7]; }
    #pragma unroll
    for (int m = 8; m >= 1; m >>= 1) lsum += __shfl_xor(lsum, m, 16);
    const float inv = 1.f / lsum;
    #pragma unroll
    for (int t7 = 0; t7 < 7; t7++) sP[qg][j + t7*16] = pv[t7] * inv;
  }
  __syncthreads();
  if (qg < 14) {
    const int s = qc*14 + qg;
    float o0 = 0.f, o1 = 0.f;
    for (int kk = 0; kk < 112; kk++) {
      const float p = sP[qg][kk];
      o0 += p * sV[kk*33 + j];
      o1 += p * sV[kk*33 + j + 16];
    }
    float* op = o + ((size_t)b*112 + s)*128 + h*32;
    op[j] = o0;
    op[j + 16] = o1;
  }
}

// ---------------- FUSED out-proj + residual + LN1 + FFN + residual + LN2, 7 rows/block
__global__ __launch_bounds__(256) void k_tail(
    const float* __restrict__ o, const float* __restrict__ zbuf,
    const int* __restrict__ sel,
    const float* __restrict__ owt, const float* __restrict__ ob,
    const float* __restrict__ l1g, const float* __restrict__ l1b,
    const float* __restrict__ f1wt, const float* __restrict__ f1b,
    const float* __restrict__ f2wt, const float* __restrict__ f2b,
    const float* __restrict__ l2g, const float* __restrict__ l2b,
    float* __restrict__ h2)
{
  __shared__ float sO[7][128];
  __shared__ float sh[7][128];
  __shared__ float sf[7][512];
  __shared__ float sV[7][128];
  __shared__ float sMean[7], sRstd[7];
  const int s0 = blockIdx.x * 7, b = blockIdx.y;
  const int tid = threadIdx.x;
  const int d = tid & 127, half = tid >> 7;
  const int r0 = half * 4;                 // half0: rows 0..3, half1: rows 4..6
  const int nr = half ? 3 : 4;

  // ---- phase 1: out-proj + residual + LN1 -> sh ----
  for (int idx = tid; idx < 7*128; idx += 256) {
    const int r = idx >> 7, dd = idx & 127;
    sO[r][dd] = o[((size_t)b*112 + s0 + r)*128 + dd];
  }
  __syncthreads();
  {
    float acc[4];
    #pragma unroll
    for (int rr = 0; rr < 4; rr++) acc[rr] = ob[d];
    for (int kk = 0; kk < 128; kk++) {
      const float wv = owt[kk*128 + d];
      #pragma unroll
      for (int rr = 0; rr < 4; rr++) {
        const int rowi = (r0 + rr < 7) ? (r0 + rr) : 6;
        acc[rr] += wv * sO[rowi][kk];
      }
    }
    #pragma unroll
    for (int rr = 0; rr < 4; rr++) {
      if (rr < nr) {
        int row = sel[b*112 + s0 + r0 + rr];
        row = row < 0 ? 0 : (row > 224 ? 224 : row);
        acc[rr] += zbuf[((size_t)b*225 + row)*128 + d];
        sV[r0 + rr][d] = acc[rr];
      }
    }
  }
  __syncthreads();
  {
    const int r = tid >> 4, j = tid & 15;
    if (r < 7) {
      float p1 = 0.f, p2 = 0.f;
      #pragma unroll
      for (int i = 0; i < 8; i++) { float v = sV[r][j*8 + i]; p1 += v; p2 += v*v; }
      #pragma unroll
      for (int m = 8; m >= 1; m >>= 1) {
        p1 += __shfl_xor(p1, m, 64);
        p2 += __shfl_xor(p2, m, 64);
      }
      if (j == 0) {
        const float mean = p1 * (1.f/128.f);
        sMean[r] = mean;
        sRstd[r] = rsqrtf(p2 * (1.f/128.f) - mean*mean + 1e-5f);
      }
    }
  }
  __syncthreads();
  for (int idx = tid; idx < 7*128; idx += 256) {
    const int r = idx >> 7, dd = idx & 127;
    sh[r][dd] = (sV[r][dd] - sMean[r]) * sRstd[r] * l1g[dd] + l1b[dd];
  }
  __syncthreads();

  // ---- phase 2: FFN + residual + LN2 -> h2 ----
  {
    float a0[7], a1[7];
    const float b0 = f1b[tid], b1 = f1b[tid + 256];
    #pragma unroll
    for (int r = 0; r < 7; r++) { a0[r] = b0; a1[r] = b1; }
    for (int kk = 0; kk < 128; kk++) {
      const float w0 = f1wt[kk*512 + tid];
      const float w1 = f1wt[kk*512 + tid + 256];
      #pragma unroll
      for (int r = 0; r < 7; r++) {
        const float xv = sh[r][kk];
        a0[r] += w0 * xv;
        a1[r] += w1 * xv;
      }
    }
    #pragma unroll
    for (int r = 0; r < 7; r++) {
      sf[r][tid]       = fmaxf(a0[r], 0.f);
      sf[r][tid + 256] = fmaxf(a1[r], 0.f);
    }
  }
  __syncthreads();
  {
    float acc[4];
    #pragma unroll
    for (int rr = 0; rr < 4; rr++) acc[rr] = f2b[d];
    for (int kk = 0; kk < 512; kk++) {
      const float wv = f2wt[kk*128 + d];
      #pragma unroll
      for (int rr = 0; rr < 4; rr++) {
        const int rowi = (r0 + rr < 7) ? (r0 + rr) : 6;
        acc[rr] += wv * sf[rowi][kk];
      }
    }
    #pragma unroll
    for (int rr = 0; rr < 4; rr++)
      if (rr < nr)
        sV[r0 + rr][d] = sh[r0 + rr][d] + acc[rr];
  }
  __syncthreads();
  {
    const int r = tid >> 4, j = tid & 15;
    if (r < 7) {
      float p1 = 0.f, p2 = 0.f;
      #pragma unroll
      for (int i = 0; i < 8; i++) { float v = sV[r][j*8 + i]; p1 += v; p2 += v*v; }
      #pragma unroll
      for (int m = 8; m >= 1; m >>= 1) {
        p1 += __shfl_xor(p1, m, 64);
        p2 += __shfl_xor(p2, m, 64);
      }
      if (j == 0) {
        const float mean = p1 * (1.f/128.f);
        sMean[r] = mean;
        sRstd[r] = rsqrtf(p2 * (1.f/128.f) - mean*mean + 1e-5f);
      }
    }
  }
  __syncthreads();
  for (int idx = tid; idx < 7*128; idx += 256) {
    const int r = idx >> 7, dd = idx & 127;
    h2[((size_t)b*112 + s0 + r)*128 + dd] =
        (sV[r][dd] - sMean[r]) * sRstd[r] * l2g[dd] + l2b[dd];
  }
}

// ---------------- rep = sum_s h2 ; classifier -> logits (f32)
__global__ __launch_bounds__(64) void k_cls(
    const float* __restrict__ h2,
    const float* __restrict__ c1w, const float* __restrict__ c1b,
    const float* __restrict__ c2w, const float* __restrict__ c2b,
    float* __restrict__ out)
{
  __shared__ float sr[128], sc[64];
  const int b = blockIdx.x, tid = threadIdx.x;
  float r0 = 0.f, r1 = 0.f;
  for (int s2 = 0; s2 < 112; s2++) {
    const float* row = h2 + ((size_t)b*112 + s2)*128;
    r0 += row[tid];
    r1 += row[tid + 64];
  }
  sr[tid] = r0; sr[tid + 64] = r1;
  __syncthreads();
  float acc = c1b[tid];
  const float* wr = c1w + (size_t)tid * 128;
  for (int kk = 0; kk < 128; kk++) acc += wr[kk] * sr[kk];
  sc[tid] = fmaxf(acc, 0.f);
  __syncthreads();
  if (tid < 2) {
    float l = c2b[tid];
    for (int kk = 0; kk < 64; kk++) l += c2w[tid*64 + kk] * sc[kk];
    out[b*2 + tid] = l;
  }
}

extern "C" void kernel_launch(void* const* d_in, const int* in_sizes, int n_in,
                              void* d_out, int out_size, void* d_ws, size_t ws_size,
                              hipStream_t stream)
{
  const float* x    = (const float*)d_in[0];
  const float* c1w  = (const float*)d_in[1];
  const float* c1b  = (const float*)d_in[2];
  const float* bn1g = (const float*)d_in[3];
  const float* bn1b = (const float*)d_in[4];
  const float* c2w  = (const float*)d_in[5];
  const float* c2b  = (const float*)d_in[6];
  const float* bn2g = (const float*)d_in[7];
  const float* bn2b = (const float*)d_in[8];
  const float* pjw  = (const float*)d_in[9];
  const float* pjb  = (const float*)d_in[10];
  const float* w1w  = (const float*)d_in[11];
  const float* w1b  = (const float*)d_in[12];
  const float* w2w  = (const float*)d_in[13];
  const float* w2b  = (const float*)d_in[14];
  const float* gw   = (const float*)d_in[15];
  const float* gb   = (const float*)d_in[16];
  const float* scw  = (const float*)d_in[17];
  const float* scb  = (const float*)d_in[18];
  const float* ipw  = (const float*)d_in[19];
  const float* ipb  = (const float*)d_in[20];
  const float* opw  = (const float*)d_in[21];
  const float* opb  = (const float*)d_in[22];
  const float* f1w  = (const float*)d_in[23];
  const float* f1b  = (const float*)d_in[24];
  const float* f2w  = (const float*)d_in[25];
  const float* f2b  = (const float*)d_in[26];
  const float* l1g  = (const float*)d_in[27];
  const float* l1b  = (const float*)d_in[28];
  const float* l2g  = (const float*)d_in[29];
  const float* l2b  = (const float*)d_in[30];
  const float* cl1w = (const float*)d_in[31];
  const float* cl1b = (const float*)d_in[32];
  const float* cl2w = (const float*)d_in[33];
  const float* cl2b = (const float*)d_in[34];

  // ---- bump allocator over d_ws (256-B aligned) ----
  char* p = (char*)d_ws;
  auto alloc = [&](size_t n) { char* r = p; p += (n + 255) & ~(size_t)255; return r; };
  u64*   mask2  = (u64*)  alloc(900    * sizeof(u64));
  int*   nbr1   = (int*)  alloc(1800   * sizeof(int));
  int*   sel    = (int*)  alloc(1792   * sizeof(int));
  float* scores = (float*)alloc(3600   * sizeof(float));
  u16*   pwh    = (u16*)  alloc(524288 * sizeof(u16));
  u16*   pwl    = (u16*)  alloc(524288 * sizeof(u16));
  u16*   wc2h   = (u16*)  alloc(36864  * sizeof(u16));
  u16*   wc2l   = (u16*)  alloc(36864  * sizeof(u16));
  u16*   wc1h   = (u16*)  alloc(2048   * sizeof(u16));
  u16*   wc1l   = (u16*)  alloc(2048   * sizeof(u16));
  float* iwt    = (float*)alloc(49152  * sizeof(float));
  float* owt    = (float*)alloc(16384  * sizeof(float));
  float* f1wt   = (float*)alloc(65536  * sizeof(float));
  float* f2wt   = (float*)alloc(65536  * sizeof(float));
  float* w1t    = (float*)alloc(16384  * sizeof(float));
  float* w2t    = (float*)alloc(16384  * sizeof(float));
  float* gwt    = (float*)alloc(32768  * sizeof(float));
  float* partial= (float*)alloc(8ull*16*225*128 * sizeof(float));  // 14.7 MB split-K=8
  float* zbuf   = (float*)alloc(460800 * sizeof(float));
  float* nodes  = (float*)alloc(460800 * sizeof(float));
  const size_t fixed_bytes = (size_t)(p - (char*)d_ws);

  const size_t qkv_bytes = 3ull * 229376ull * sizeof(float);
  const size_t per_batch = 64ull*128*128*2 + 64ull*64*64*2;   // 2,621,440 B
  int BC = 16;
  size_t s3 = 0;
  for (;; BC >>= 1) {
    s3 = (size_t)BC * per_batch; if (s3 < qkv_bytes) s3 = qkv_bytes;
    if (fixed_bytes + s3 + 65536 <= ws_size) break;
    if (BC == 1) { return; }
  }
  char* S3 = alloc(s3);

  u16*   feat1 = (u16*)S3;                              // NHWC (BC,128,128,64)
  u16*   feat2 = (u16*)(S3 + (size_t)BC * 2097152ull);  // NCHW (BC,64,64,64)
  float* qb    = (float*)S3;
  float* kb    = qb + 229376;
  float* vb    = kb + 229376;
  float* obuf  = nodes;                                 // nodes dead after k_gz2
  float* hbuf  = nodes + 229376;                        // h2

  k_prep<<<1913, 256, 0, stream>>>(pjw, pwh, pwl, c2w, bn2g, wc2h, wc2l,
                                   c1w, bn1g, wc1h, wc1l,
                                   ipw, iwt, opw, owt, f1w, f1wt, f2w, f2wt,
                                   w1w, w1t, w2w, w2t, gw, gwt, nbr1);
  k_adj2<<<1, 256, 0, stream>>>(nbr1, mask2);

  for (int b0 = 0; b0 < 16; b0 += BC) {
    k_conv1m<<<dim3(16,16,BC), 256, 0, stream>>>(x, wc1h, wc1l, c1b, bn1g, bn1b, feat1, b0);
    k_conv2m<<<dim3(4,8,BC), 256, 0, stream>>>(feat1, wc2h, wc2l, c2b, bn2g, bn2b, feat2);
    k_projm <<<dim3(4,8,BC), 256, 0, stream>>>(feat2, pwh, pwl, partial, b0);
    k_projr <<<dim3(225,BC), 128, 0, stream>>>(partial, pjb, nodes, b0);
  }

  k_gz2  <<<900, 256, 0, stream>>>(nodes, nbr1, mask2, w1t, w1b, w2t, w2b,
                                   gwt, gb, scw, scb, zbuf, scores);
  k_topk <<<16, 256, 0, stream>>>(scores, sel);
  k_qkv  <<<dim3(16,16), 256, 0, stream>>>(zbuf, sel, iwt, ipb, qb, kb, vb);
  k_attn <<<dim3(8,4,16), 256, 0, stream>>>(qb, kb, vb, obuf);
  k_tail <<<dim3(16,16), 256, 0, stream>>>(obuf, zbuf, sel, owt, opb, l1g, l1b,
                                           f1wt, f1b, f2wt, f2b, l2g, l2b, hbuf);
  k_cls  <<<16, 64, 0, stream>>>(hbuf, cl1w, cl1b, cl2w, cl2b, (float*)d_out);
}

// Round 27
// 247.504 us; speedup vs baseline: 1.1771x; 1.0374x over previous
//
#include <hip/hip_runtime.h>
#include <hip/hip_bf16.h>
#include <math.h>

typedef unsigned short u16;
typedef unsigned int   u32;
typedef unsigned long long u64;
typedef __attribute__((ext_vector_type(8))) short short8v;
typedef __attribute__((ext_vector_type(4))) float f32x4;

__device__ __forceinline__ float bf2f(u16 u) {
  union { u32 i; float f; } v; v.i = ((u32)u) << 16; return v.f;
}
__device__ __forceinline__ u16 f2bf(float f) {  // round-to-nearest-even
  union { float f; u32 i; } v; v.f = f;
  u32 r = (v.i + 0x7FFFu + ((v.i >> 16) & 1u)) >> 16;
  return (u16)r;
}

// ---------------- conv1 + bn1 + relu + maxpool2 via MFMA im2col (K=32, hi/lo input split)
// T2 XOR chunk swizzle on sA*/sB* (write chunk = logical ^ (row&3); read likewise)
__global__ __launch_bounds__(256, 2) void k_conv1m(
    const float* __restrict__ x,
    const u16* __restrict__ wh, const u16* __restrict__ wl,
    const float* __restrict__ cb, const float* __restrict__ g, const float* __restrict__ bb,
    u16* __restrict__ feat1, int b0)
{
  __shared__ __align__(16) u16 sInH[3*18*18], sInL[3*18*18];
  __shared__ __align__(16) u16 sAh[256*40], sAl[256*40];
  __shared__ __align__(16) u16 sBh[64*40],  sBl[64*40];
  __shared__ float sBias[64];
  const int tx = blockIdx.x, ty = blockIdx.y, bl = blockIdx.z;
  const int b = b0 + bl;
  const int y0 = ty*16, x0 = tx*16;
  const int tid = threadIdx.x;
  const int w = tid >> 6, l = tid & 63, lr = l & 15, lk = l >> 4;

  if (tid < 64) {
    float sc = g[tid] * rsqrtf(1.0f + 1e-5f);
    sBias[tid] = cb[tid] * sc + bb[tid];
  }
  {
    const int oc = tid >> 2, seg = tid & 3;
    const int ps = seg ^ (oc & 3);           // swizzled chunk
    *reinterpret_cast<uint4*>(&sBh[oc*40 + ps*8]) =
        *reinterpret_cast<const uint4*>(wh + oc*32 + seg*8);
    *reinterpret_cast<uint4*>(&sBl[oc*40 + ps*8]) =
        *reinterpret_cast<const uint4*>(wl + oc*32 + seg*8);
  }
  for (int i = tid; i < 3*18*18; i += 256) {
    const int c = i / 324, r = (i / 18) % 18, q = i % 18;
    const int yy = y0 - 1 + r, xx = x0 - 1 + q;
    float v = 0.f;
    if (yy >= 0 && yy < 256 && xx >= 0 && xx < 256)
      v = x[(((size_t)b*3 + c)*256 + yy)*256 + xx];
    const u16 h = f2bf(v);
    sInH[i] = h;
    sInL[i] = f2bf(v - bf2f(h));
  }
  __syncthreads();
  {
    const int py = tid >> 4, px = tid & 15;
    u32 hw[16], lw[16];
    #pragma unroll
    for (int i = 0; i < 16; i++) { hw[i] = 0u; lw[i] = 0u; }
    #pragma unroll
    for (int c = 0; c < 3; c++)
      #pragma unroll
      for (int ky = 0; ky < 3; ky++)
        #pragma unroll
        for (int kx = 0; kx < 3; kx++) {
          const int k = c*9 + ky*3 + kx;
          const int src = (c*18 + py + ky)*18 + px + kx;
          hw[k >> 1] |= ((u32)sInH[src]) << ((k & 1)*16);
          lw[k >> 1] |= ((u32)sInL[src]) << ((k & 1)*16);
        }
    #pragma unroll
    for (int s = 0; s < 4; s++) {
      const int ps = s ^ (tid & 3);          // swizzled chunk
      uint4 vh, vl;
      vh.x = hw[s*4+0]; vh.y = hw[s*4+1]; vh.z = hw[s*4+2]; vh.w = hw[s*4+3];
      vl.x = lw[s*4+0]; vl.y = lw[s*4+1]; vl.z = lw[s*4+2]; vl.w = lw[s*4+3];
      *reinterpret_cast<uint4*>(&sAh[tid*40 + ps*8]) = vh;
      *reinterpret_cast<uint4*>(&sAl[tid*40 + ps*8]) = vl;
    }
  }
  __syncthreads();
  f32x4 acc[4][4];
  #pragma unroll
  for (int j = 0; j < 4; j++)
    #pragma unroll
    for (int ct = 0; ct < 4; ct++)
      acc[j][ct] = (f32x4){0.f,0.f,0.f,0.f};
  const int lkA = lk ^ (lr & 3);             // swizzled read chunk (pix&3 == lr&3)
  #pragma unroll
  for (int j = 0; j < 4; j++) {
    const int mt = w*4 + j;
    const short8v ah = *reinterpret_cast<const short8v*>(&sAh[(mt*16 + lr)*40 + lkA*8]);
    const short8v al = *reinterpret_cast<const short8v*>(&sAl[(mt*16 + lr)*40 + lkA*8]);
    #pragma unroll
    for (int ct = 0; ct < 4; ct++) {
      const short8v bh = *reinterpret_cast<const short8v*>(&sBh[(ct*16 + lr)*40 + lkA*8]);
      const short8v bv = *reinterpret_cast<const short8v*>(&sBl[(ct*16 + lr)*40 + lkA*8]);
      acc[j][ct] = __builtin_amdgcn_mfma_f32_16x16x32_bf16(ah, bh, acc[j][ct], 0, 0, 0);
      acc[j][ct] = __builtin_amdgcn_mfma_f32_16x16x32_bf16(ah, bv, acc[j][ct], 0, 0, 0);
      acc[j][ct] = __builtin_amdgcn_mfma_f32_16x16x32_bf16(al, bh, acc[j][ct], 0, 0, 0);
    }
  }
  #pragma unroll
  for (int j = 0; j < 2; j++) {
    const int jA = 2*j, jB = 2*j + 1;
    const int oy = ty*8 + w*2 + j;
    #pragma unroll
    for (int xh = 0; xh < 2; xh++) {
      const int ox = tx*8 + lk*2 + xh;
      #pragma unroll
      for (int ct = 0; ct < 4; ct++) {
        const int oc = ct*16 + lr;
        float m = fmaxf(fmaxf(acc[jA][ct][2*xh], acc[jA][ct][2*xh+1]),
                        fmaxf(acc[jB][ct][2*xh], acc[jB][ct][2*xh+1]));
        m = fmaxf(m + sBias[oc], 0.f);
        feat1[(((size_t)bl*128 + oy)*128 + ox)*64 + oc] = f2bf(m);
      }
    }
  }
}

// ---------------- conv2 + bn2 + relu + maxpool2 via MFMA implicit GEMM (B dbuf, T2 swizzle)
__global__ __launch_bounds__(256, 2) void k_conv2m(
    const u16* __restrict__ feat1,
    const u16* __restrict__ wh, const u16* __restrict__ wl,
    const float* __restrict__ cb, const float* __restrict__ g, const float* __restrict__ bb,
    u16* __restrict__ feat2)
{
  __shared__ __align__(16) u16 sA[18*34*40];
  __shared__ __align__(16) u16 sBh[2][64*40], sBl[2][64*40];
  __shared__ float sBias[64];
  const int tx = blockIdx.x, ty = blockIdx.y, bl = blockIdx.z;
  const int y0 = ty*16, x0 = tx*32;
  const int tid = threadIdx.x;
  const int w = tid >> 6, l = tid & 63;
  const int lr = l & 15, lk = l >> 4;

  if (tid < 64) {
    float sc = g[tid] * rsqrtf(1.0f + 1e-5f);
    sBias[tid] = cb[tid] * sc + bb[tid];
  }

  f32x4 acc[8][4];
  #pragma unroll
  for (int j = 0; j < 8; j++)
    #pragma unroll
    for (int ct = 0; ct < 4; ct++)
      acc[j][ct] = (f32x4){0.f,0.f,0.f,0.f};

  const int ocB = tid >> 2;
  const int psB = (tid & 3) ^ (ocB & 3);     // swizzled B chunk
  uint4 rBh, rBl;
  auto ldB = [&](int chunk, int kk) {
    const size_t src = (size_t)(kk*2 + chunk)*2048 + tid*8;
    rBh = *reinterpret_cast<const uint4*>(wh + src);
    rBl = *reinterpret_cast<const uint4*>(wl + src);
  };
  auto stB = [&](int buf) {
    *reinterpret_cast<uint4*>(&sBh[buf][ocB*40 + psB*8]) = rBh;
    *reinterpret_cast<uint4*>(&sBl[buf][ocB*40 + psB*8]) = rBl;
  };

  const int lkB = lk ^ (lr & 3);             // swizzled B read chunk
  for (int chunk = 0; chunk < 2; chunk++) {
    __syncthreads();
    ldB(chunk, 0);
    for (int idx = tid; idx < 612*4; idx += 256) {
      const int pix = idx >> 2, seg = idx & 3;
      const int r = pix / 34, cc = pix % 34;
      const int yy = y0 - 1 + r, xx = x0 - 1 + cc;
      uint4 v = {0u,0u,0u,0u};
      if (yy >= 0 && yy < 128 && xx >= 0 && xx < 128)
        v = *reinterpret_cast<const uint4*>(
              feat1 + (((size_t)bl*128 + yy)*128 + xx)*64 + chunk*32 + seg*8);
      const int ps = seg ^ (pix & 3);        // swizzled A chunk
      *reinterpret_cast<uint4*>(&sA[(size_t)pix*40 + ps*8]) = v;
    }
    stB(0);
    __syncthreads();
    int cur = 0;
    for (int kk = 0; kk < 9; kk++) {
      if (kk + 1 < 9) ldB(chunk, kk + 1);
      const int ky = kk / 3, kx = kk % 3;
      short8v a[8];
      #pragma unroll
      for (int j = 0; j < 8; j++) {
        const int m = w*8 + j;
        const int r = (m >> 1) + ky;
        const int cc = (m & 1)*16 + lr + kx;
        const int pixR = r*34 + cc;
        const int lkR = lk ^ (pixR & 3);     // swizzled A read chunk
        a[j] = *reinterpret_cast<const short8v*>(&sA[(size_t)pixR*40 + lkR*8]);
      }
      #pragma unroll
      for (int ct = 0; ct < 4; ct++) {
        const short8v bh = *reinterpret_cast<const short8v*>(&sBh[cur][(ct*16 + lr)*40 + lkB*8]);
        const short8v bv = *reinterpret_cast<const short8v*>(&sBl[cur][(ct*16 + lr)*40 + lkB*8]);
        #pragma unroll
        for (int j = 0; j < 8; j++) {
          acc[j][ct] = __builtin_amdgcn_mfma_f32_16x16x32_bf16(a[j], bh, acc[j][ct], 0, 0, 0);
          acc[j][ct] = __builtin_amdgcn_mfma_f32_16x16x32_bf16(a[j], bv, acc[j][ct], 0, 0, 0);
        }
      }
      if (kk + 1 < 9) {
        stB(cur ^ 1);
        __syncthreads();
        cur ^= 1;
      }
    }
  }
  #pragma unroll
  for (int u = 0; u < 2; u++) {
    #pragma unroll
    for (int xh = 0; xh < 2; xh++) {
      const int jA = 4*u + xh, jB = 4*u + 2 + xh;
      #pragma unroll
      for (int ct = 0; ct < 4; ct++) {
        const int oc = ct*16 + lr;
        const float bias = sBias[oc];
        const float v0 = fmaxf(fmaxf(acc[jA][ct][0], acc[jA][ct][1]),
                               fmaxf(acc[jB][ct][0], acc[jB][ct][1]));
        const float v1 = fmaxf(fmaxf(acc[jA][ct][2], acc[jA][ct][3]),
                               fmaxf(acc[jB][ct][2], acc[jB][ct][3]));
        const u16 b0v = f2bf(fmaxf(v0 + bias, 0.f));
        const u16 b1v = f2bf(fmaxf(v1 + bias, 0.f));
        const int py = ty*8 + 2*w + u;
        const int px = tx*16 + xh*8 + lk*2;
        u32 pk = (u32)b0v | ((u32)b1v << 16);
        *reinterpret_cast<u32*>(&feat2[(((size_t)bl*64 + oc)*64 + py)*64 + px]) = pk;
      }
    }
  }
}

// ---------------- adjacency phase 2: mask2 = rows of (adj@adj>0) minus diagonal
__global__ __launch_bounds__(256) void k_adj2(
    const int* __restrict__ nbr1, u64* __restrict__ mask2)
{
  const int i = threadIdx.x;
  if (i >= 225) return;
  u64 m0=0, m1=0, m2=0, m3=0;
  #pragma unroll
  for (int t = 0; t < 8; t++) {
    const int tt = nbr1[i*8 + t];
    #pragma unroll
    for (int u = 0; u < 8; u++) {
      const int j = nbr1[tt*8 + u];
      const u64 bset = 1ull << (j & 63);
      const int wd = j >> 6;
      m0 |= (wd == 0) ? bset : 0ull;
      m1 |= (wd == 1) ? bset : 0ull;
      m2 |= (wd == 2) ? bset : 0ull;
      m3 |= (wd == 3) ? bset : 0ull;
    }
  }
  {
    const u64 bc = ~(1ull << (i & 63));
    const int wd = i >> 6;
    if (wd == 0) m0 &= bc; else if (wd == 1) m1 &= bc;
    else if (wd == 2) m2 &= bc; else m3 &= bc;
  }
  mask2[i*4+0] = m0; mask2[i*4+1] = m1; mask2[i*4+2] = m2; mask2[i*4+3] = m3;
}

// ---------------- fused weight prep + adjacency 8-NN (blocks >= 1688)
__global__ __launch_bounds__(256) void k_prep(
    const float* __restrict__ pjw, u16* __restrict__ pwh, u16* __restrict__ pwl,
    const float* __restrict__ c2w, const float* __restrict__ bn2g,
    u16* __restrict__ wc2h, u16* __restrict__ wc2l,
    const float* __restrict__ c1w, const float* __restrict__ bn1g,
    u16* __restrict__ wc1h, u16* __restrict__ wc1l,
    const float* __restrict__ ipw, float* __restrict__ iwt,
    const float* __restrict__ opw, float* __restrict__ owt,
    const float* __restrict__ f1w, float* __restrict__ f1wt,
    const float* __restrict__ f2w, float* __restrict__ f2wt,
    const float* __restrict__ w1w, float* __restrict__ w1t,
    const float* __restrict__ w2w, float* __restrict__ w2t,
    const float* __restrict__ gw,  float* __restrict__ gwt,
    int* __restrict__ nbr1)
{
  __shared__ int skey[256];
  __shared__ int sred[256];
  const int blk = blockIdx.x, tid = threadIdx.x;
  if (blk < 512) {
    const int i = (blk*256 + tid) * 4;
    float4 v = *reinterpret_cast<const float4*>(pjw + i);
    float e[4] = {v.x, v.y, v.z, v.w};
    ushort4 h, l;
    u16* hp = &h.x; u16* lp = &l.x;
    #pragma unroll
    for (int j = 0; j < 4; j++) {
      u16 hb = f2bf(e[j]);
      hp[j] = hb;
      lp[j] = f2bf(e[j] - bf2f(hb));
    }
    *reinterpret_cast<ushort4*>(pwh + i) = h;
    *reinterpret_cast<ushort4*>(pwl + i) = l;
  } else if (blk < 656) {
    const int d = (blk - 512)*256 + tid;
    if (d < 36864) {
      const int icL = d & 31, oc = (d >> 5) & 63, chunk = (d >> 11) & 1, kk = d >> 12;
      const float sc = bn2g[oc] * rsqrtf(1.0f + 1e-5f);
      const float val = c2w[((size_t)oc*64 + chunk*32 + icL)*9 + kk] * sc;
      const u16 hb = f2bf(val);
      wc2h[d] = hb;
      wc2l[d] = f2bf(val - bf2f(hb));
    }
  } else if (blk < 664) {
    const int d = (blk - 656)*256 + tid;
    if (d < 2048) {
      const int k = d & 31, oc = d >> 5;
      float val = 0.f;
      if (k < 27) val = c1w[oc*27 + k] * (bn1g[oc] * rsqrtf(1.0f + 1e-5f));
      const u16 hb = f2bf(val);
      wc1h[d] = hb;
      wc1l[d] = f2bf(val - bf2f(hb));
    }
  } else if (blk < 1688) {
    const float* src; float* dst; int O, K, base;
    if      (blk <  856) { src = ipw; dst = iwt;  O = 384; K = 128; base = 664;  }
    else if (blk <  920) { src = opw; dst = owt;  O = 128; K = 128; base = 856;  }
    else if (blk < 1176) { src = f1w; dst = f1wt; O = 512; K = 128; base = 920;  }
    else if (blk < 1432) { src = f2w; dst = f2wt; O = 128; K = 512; base = 1176; }
    else if (blk < 1496) { src = w1w; dst = w1t;  O = 128; K = 128; base = 1432; }
    else if (blk < 1560) { src = w2w; dst = w2t;  O = 128; K = 128; base = 1496; }
    else                 { src = gw;  dst = gwt;  O = 128; K = 256; base = 1560; }
    const int idx = (blk - base)*256 + tid;
    if (idx < O * K) {
      const int o = idx / K, k = idx % K;
      dst[(size_t)k * O + o] = src[idx];
    }
  } else {
    const int i = blk - 1688;
    int key = 0x7FFFFFFF;
    if (tid < 225 && tid != i) {
      const int di = i/15 - tid/15, dj = i%15 - tid%15;
      key = (di*di + dj*dj)*256 + tid;
    }
    skey[tid] = key;
    __syncthreads();
    for (int t = 0; t < 8; t++) {
      sred[tid] = skey[tid];
      __syncthreads();
      #pragma unroll
      for (int st = 128; st > 0; st >>= 1) {
        if (tid < st) sred[tid] = min(sred[tid], sred[tid+st]);
        __syncthreads();
      }
      const int wj = sred[0] & 255;
      if (tid == 0) nbr1[i*8 + t] = wj;
      __syncthreads();
      if (tid == wj) skey[tid] = 0x7FFFFFFF;
      __syncthreads();
    }
  }
}

// ---------------- patch-projection MFMA GEMM, split-K=8, A direct-load w/ 1-step register
// prefetch, B dbuf + T2 swizzle (64-row tiles, grid 4x8x16)
__global__ __launch_bounds__(256, 2) void k_projm(
    const u16* __restrict__ feat2,
    const u16* __restrict__ pwh, const u16* __restrict__ pwl,
    float* __restrict__ partial, int b0)
{
  __shared__ __align__(16) u16 sBh[2][128*40];
  __shared__ __align__(16) u16 sBl[2][128*40];
  const int cx = blockIdx.x, kc = blockIdx.y, bl = blockIdx.z;
  const int b  = b0 + bl;
  const int n0 = cx * 64;
  const int rows = (225 - n0) < 64 ? (225 - n0) : 64;
  const int tid = threadIdx.x;
  const int w = tid >> 6, l = tid & 63;
  const int lr = l & 15, lk = l >> 4;

  f32x4 acc[8];
  #pragma unroll
  for (int i = 0; i < 8; i++) acc[i] = (f32x4){0.f, 0.f, 0.f, 0.f};

  int an = n0 + w*16 + lr;
  if (an > 224) an = 224;
  const int aph = an / 15, apw = an % 15;
  const int kbeg = kc * 512, kend = kbeg + 512;

  uint4 rBh[2], rBl[2];
  auto ldB = [&](int k0) {
    #pragma unroll
    for (int p = 0; p < 2; p++) {
      const int idx = p*256 + tid;
      const int col = idx >> 2, seg = idx & 3;
      const size_t off = (size_t)col*4096 + k0 + seg*8;
      rBh[p] = *reinterpret_cast<const uint4*>(pwh + off);
      rBl[p] = *reinterpret_cast<const uint4*>(pwl + off);
    }
  };
  auto stB = [&](int buf) {
    #pragma unroll
    for (int p = 0; p < 2; p++) {
      const int idx = p*256 + tid;
      const int col = idx >> 2, seg = idx & 3;
      const int ps = seg ^ (col & 3);        // swizzled chunk
      *reinterpret_cast<uint4*>(&sBh[buf][col*40 + ps*8]) = rBh[p];
      *reinterpret_cast<uint4*>(&sBl[buf][col*40 + ps*8]) = rBl[p];
    }
  };
  auto ldA = [&](int k0, uint2& a0, uint2& a1) {
    const int c = k0 >> 6;
    const int i = ((k0 & 32) >> 3) + lk;
    const u16* ap = feat2 + (((size_t)bl*64 + c)*64 + aph*4 + i)*64 + apw*4;
    a0 = *reinterpret_cast<const uint2*>(ap);
    a1 = *reinterpret_cast<const uint2*>(ap + 4);
  };

  const int lkB = lk ^ (lr & 3);             // swizzled read chunk
  uint2 a0c, a1c, a0n, a1n;
  ldB(kbeg);
  ldA(kbeg, a0c, a1c);
  stB(0);
  __syncthreads();
  int cur = 0;
  for (int k0 = kbeg; k0 < kend; k0 += 32) {
    const bool more = (k0 + 32 < kend);
    if (more) { ldB(k0 + 32); ldA(k0 + 32, a0n, a1n); }
    union { short8v v; uint2 u[2]; } a;
    a.u[0] = a0c; a.u[1] = a1c;
    #pragma unroll
    for (int ct = 0; ct < 8; ct++) {
      const short8v bh = *reinterpret_cast<const short8v*>(&sBh[cur][(ct*16 + lr)*40 + lkB*8]);
      const short8v bv = *reinterpret_cast<const short8v*>(&sBl[cur][(ct*16 + lr)*40 + lkB*8]);
      acc[ct] = __builtin_amdgcn_mfma_f32_16x16x32_bf16(a.v, bh, acc[ct], 0, 0, 0);
      acc[ct] = __builtin_amdgcn_mfma_f32_16x16x32_bf16(a.v, bv, acc[ct], 0, 0, 0);
    }
    if (more) {
      stB(cur ^ 1);
      __syncthreads();
      cur ^= 1;
      a0c = a0n; a1c = a1n;
    }
  }
  #pragma unroll
  for (int ct = 0; ct < 8; ct++) {
    const int col = ct*16 + lr;
    #pragma unroll
    for (int v = 0; v < 4; v++) {
      const int r = w*16 + lk*4 + v;
      if (r < rows)
        partial[(((size_t)kc*16 + b)*225 + n0 + r)*128 + col] = acc[ct][v];
    }
  }
}

// ---------------- reduce split-K partials + bias -> nodes
__global__ __launch_bounds__(128) void k_projr(
    const float* __restrict__ partial, const float* __restrict__ pb,
    float* __restrict__ nodes, int b0)
{
  const int n = blockIdx.x, bl = blockIdx.y;
  const int b = b0 + bl;
  const int d = threadIdx.x;
  float s = pb[d];
  #pragma unroll
  for (int kc = 0; kc < 8; kc++)
    s += partial[(((size_t)kc*16 + b)*225 + n)*128 + d];
  nodes[((size_t)b*225 + n)*128 + d] = s;
}

// ---------------- FUSED gather + z1/z2/gate/score: 4 rows per block (900 blocks)
__global__ __launch_bounds__(256) void k_gz2(
    const float* __restrict__ nodes, const int* __restrict__ nbr1,
    const u64* __restrict__ mask2,
    const float* __restrict__ w1t, const float* __restrict__ w1b,
    const float* __restrict__ w2t, const float* __restrict__ w2b,
    const float* __restrict__ gwt, const float* __restrict__ gb,
    const float* __restrict__ sw, const float* __restrict__ sb,
    float* __restrict__ zbuf, float* __restrict__ scores)
{
  __shared__ float sA1[4][128], sA2[4][128], sC[4][256], sRed[4][128];
  const int row0 = blockIdx.x * 4;
  const int tid = threadIdx.x;
  const int d = tid & 127, rr = tid >> 7;
  #pragma unroll
  for (int q = 0; q < 2; q++) {
    const int lrow = rr*2 + q;
    const int row = row0 + lrow;
    const int b = row / 225, n = row % 225;
    const float* nb = nodes + (size_t)b * 225 * 128;
    float a1 = 0.f;
    #pragma unroll
    for (int t = 0; t < 8; t++) a1 += nb[(size_t)nbr1[n*8+t]*128 + d];
    float a2 = 0.f;
    for (int wd = 0; wd < 4; wd++) {
      u64 m = mask2[n*4 + wd];
      while (m) {
        int j = wd*64 + __builtin_ctzll(m);
        a2 += nb[(size_t)j*128 + d];
        m &= m - 1;
      }
    }
    sA1[lrow][d] = a1; sA2[lrow][d] = a2;
  }
  __syncthreads();
  float z1[2], z2[2];
  { const float b1 = w1b[d], b2 = w2b[d];
    z1[0] = b1; z1[1] = b1; z2[0] = b2; z2[1] = b2; }
  #pragma unroll 4
  for (int k = 0; k < 128; k++) {
    const float wv1 = w1t[k*128 + d];
    const float wv2 = w2t[k*128 + d];
    #pragma unroll
    for (int q = 0; q < 2; q++) {
      z1[q] += wv1 * sA1[rr*2 + q][k];
      z2[q] += wv2 * sA2[rr*2 + q][k];
    }
  }
  #pragma unroll
  for (int q = 0; q < 2; q++) {
    sC[rr*2 + q][d] = z1[q]; sC[rr*2 + q][128 + d] = z2[q];
  }
  __syncthreads();
  float gl[2];
  { const float bg = gb[d]; gl[0] = bg; gl[1] = bg; }
  #pragma unroll 4
  for (int k = 0; k < 256; k++) {
    const float wv = gwt[k*128 + d];
    #pragma unroll
    for (int q = 0; q < 2; q++)
      gl[q] += wv * sC[rr*2 + q][k];
  }
  const float swd = sw[d];
  #pragma unroll
  for (int q = 0; q < 2; q++) {
    const int row = row0 + rr*2 + q;
    const float gg = 1.f / (1.f + expf(-gl[q]));
    const float zv = gg * z1[q] + (1.f - gg) * z2[q];
    zbuf[(size_t)row*128 + d] = zv;
    sRed[rr*2 + q][d] = zv * swd;
  }
  __syncthreads();
  if (tid < 64) {
    const int r = tid >> 4, j = tid & 15;
    float part = 0.f;
    #pragma unroll
    for (int i = 0; i < 8; i++) part += sRed[r][j*8 + i];
    #pragma unroll
    for (int m = 8; m >= 1; m >>= 1) part += __shfl_xor(part, m, 64);
    if (j == 0) scores[row0 + r] = part + sb[0];
  }
}

// ---------------- top-k (k=112) with jax tie semantics
__global__ __launch_bounds__(256) void k_topk(
    const float* __restrict__ scores, int* __restrict__ sel)
{
  __shared__ float ss[225];
  const int b = blockIdx.x, tid = threadIdx.x;
  if (tid < 112) sel[b*112 + tid] = tid;
  if (tid < 225) ss[tid] = scores[b*225 + tid];
  __syncthreads();
  if (tid < 225) {
    float s = ss[tid];
    int rank = 0;
    for (int j = 0; j < 225; j++) {
      float sj = ss[j];
      rank += (sj > s) || (sj == s && j < tid);
    }
    if (rank < 112) sel[b*112 + rank] = tid;
  }
}

// ---------------- qkv batched: 4 rows per block (448 blocks -> ~1.75 blocks/CU)
__global__ __launch_bounds__(256) void k_qkv(
    const float* __restrict__ zbuf, const int* __restrict__ sel,
    const float* __restrict__ iwt, const float* __restrict__ ib,
    float* __restrict__ q, float* __restrict__ k, float* __restrict__ v)
{
  __shared__ float sx[4][128];
  const int s0 = blockIdx.x * 4, b = blockIdx.y;
  const int tid = threadIdx.x;
  const int c = tid & 127, half = tid >> 7;
  const int r0 = half * 2;                 // half0: rows 0-1, half1: rows 2-3

  for (int idx = tid; idx < 4*128; idx += 256) {
    const int r = idx >> 7, dd = idx & 127;
    int row = sel[b*112 + s0 + r];
    row = row < 0 ? 0 : (row > 224 ? 224 : row);
    sx[r][dd] = zbuf[((size_t)b*225 + row)*128 + dd];
  }
  __syncthreads();

  float acc[3][2];
  #pragma unroll
  for (int p = 0; p < 3; p++)
    #pragma unroll
    for (int rr = 0; rr < 2; rr++) acc[p][rr] = ib[p*128 + c];
  for (int kk = 0; kk < 128; kk++) {
    float wv[3];
    #pragma unroll
    for (int p = 0; p < 3; p++) wv[p] = iwt[kk*384 + p*128 + c];
    #pragma unroll
    for (int rr = 0; rr < 2; rr++) {
      const float xv = sx[r0 + rr][kk];
      #pragma unroll
      for (int p = 0; p < 3; p++) acc[p][rr] += wv[p] * xv;
    }
  }
  const int h = c >> 5, t = c & 31;
  float* outs[3] = {q, k, v};
  #pragma unroll
  for (int p = 0; p < 3; p++)
    #pragma unroll
    for (int rr = 0; rr < 2; rr++)
      outs[p][(((size_t)b*4 + h)*112 + s0 + r0 + rr)*32 + t] = acc[p][rr];
}

// ---------------- attention: 512 blocks (8 q-chunks x 4 heads x 16 b), 16 thr/query
__global__ __launch_bounds__(256) void k_attn(
    const float* __restrict__ q, const float* __restrict__ k,
    const float* __restrict__ v, float* __restrict__ o)
{
  __shared__ float sK[112*33], sV[112*33];
  __shared__ float sQ[14*33];
  __shared__ float sP[14][112];
  const int qc = blockIdx.x, h = blockIdx.y, b = blockIdx.z;
  const size_t base = ((size_t)b*4 + h) * 112 * 32;
  const int tid = threadIdx.x;
  for (int i = tid; i < 112*32; i += 256) {
    const int r = i >> 5, c = i & 31;
    sK[r*33 + c] = k[base + i];
    sV[r*33 + c] = v[base + i];
  }
  for (int i = tid; i < 14*32; i += 256) {
    const int r = i >> 5, c = i & 31;
    sQ[r*33 + c] = q[base + (size_t)(qc*14)*32 + i];
  }
  __syncthreads();
  const int qg = tid >> 4, j = tid & 15;
  if (qg < 14) {
    const float scale = 0.17677669529663687f;
    float pv[7];
    float mx = -INFINITY;
    #pragma unroll
    for (int t7 = 0; t7 < 7; t7++) {
      const int kk = j + t7*16;
      float s = 0.f;
      #pragma unroll
      for (int t = 0; t < 32; t++) s += sQ[qg*33 + t] * sK[kk*33 + t];
      pv[t7] = s * scale;
      mx = fmaxf(mx, pv[t7]);
    }
    #pragma unroll
    for (int m = 8; m >= 1; m >>= 1) mx = fmaxf(mx, __shfl_xor(mx, m, 16));
    float lsum = 0.f;
    #pragma unroll
    for (int t7 = 0; t7 < 7; t7++) { pv[t7] = expf(pv[t7] - mx); lsum += pv[t7]; }
    #pragma unroll
    for (int m = 8; m >= 1; m >>= 1) lsum += __shfl_xor(lsum, m, 16);
    const float inv = 1.f / lsum;
    #pragma unroll
    for (int t7 = 0; t7 < 7; t7++) sP[qg][j + t7*16] = pv[t7] * inv;
  }
  __syncthreads();
  if (qg < 14) {
    const int s = qc*14 + qg;
    float o0 = 0.f, o1 = 0.f;
    for (int kk = 0; kk < 112; kk++) {
      const float p = sP[qg][kk];
      o0 += p * sV[kk*33 + j];
      o1 += p * sV[kk*33 + j + 16];
    }
    float* op = o + ((size_t)b*112 + s)*128 + h*32;
    op[j] = o0;
    op[j + 16] = o1;
  }
}

// ---------------- FUSED out-proj + residual + LN1 + FFN + residual + LN2, 4 rows/block
// (448 blocks ~ 1.75 blocks/CU; was 256 blocks @ ~1 wave/SIMD, latency-bound)
__global__ __launch_bounds__(256) void k_tail(
    const float* __restrict__ o, const float* __restrict__ zbuf,
    const int* __restrict__ sel,
    const float* __restrict__ owt, const float* __restrict__ ob,
    const float* __restrict__ l1g, const float* __restrict__ l1b,
    const float* __restrict__ f1wt, const float* __restrict__ f1b,
    const float* __restrict__ f2wt, const float* __restrict__ f2b,
    const float* __restrict__ l2g, const float* __restrict__ l2b,
    float* __restrict__ h2)
{
  __shared__ float sO[4][128];
  __shared__ float sh[4][128];
  __shared__ float sf[4][512];
  __shared__ float sV[4][128];
  __shared__ float sMean[4], sRstd[4];
  const int s0 = blockIdx.x * 4, b = blockIdx.y;
  const int tid = threadIdx.x;
  const int d = tid & 127, half = tid >> 7;
  const int r0 = half * 2;                 // half0: rows 0-1, half1: rows 2-3

  // ---- phase 1: out-proj + residual + LN1 -> sh ----
  for (int idx = tid; idx < 4*128; idx += 256) {
    const int r = idx >> 7, dd = idx & 127;
    sO[r][dd] = o[((size_t)b*112 + s0 + r)*128 + dd];
  }
  __syncthreads();
  {
    float acc[2];
    #pragma unroll
    for (int rr = 0; rr < 2; rr++) acc[rr] = ob[d];
    for (int kk = 0; kk < 128; kk++) {
      const float wv = owt[kk*128 + d];
      #pragma unroll
      for (int rr = 0; rr < 2; rr++) acc[rr] += wv * sO[r0 + rr][kk];
    }
    #pragma unroll
    for (int rr = 0; rr < 2; rr++) {
      int row = sel[b*112 + s0 + r0 + rr];
      row = row < 0 ? 0 : (row > 224 ? 224 : row);
      acc[rr] += zbuf[((size_t)b*225 + row)*128 + d];
      sV[r0 + rr][d] = acc[rr];
    }
  }
  __syncthreads();
  {
    const int r = tid >> 4, j = tid & 15;
    if (r < 4) {
      float p1 = 0.f, p2 = 0.f;
      #pragma unroll
      for (int i = 0; i < 8; i++) { float v = sV[r][j*8 + i]; p1 += v; p2 += v*v; }
      #pragma unroll
      for (int m = 8; m >= 1; m >>= 1) {
        p1 += __shfl_xor(p1, m, 64);
        p2 += __shfl_xor(p2, m, 64);
      }
      if (j == 0) {
        const float mean = p1 * (1.f/128.f);
        sMean[r] = mean;
        sRstd[r] = rsqrtf(p2 * (1.f/128.f) - mean*mean + 1e-5f);
      }
    }
  }
  __syncthreads();
  for (int idx = tid; idx < 4*128; idx += 256) {
    const int r = idx >> 7, dd = idx & 127;
    sh[r][dd] = (sV[r][dd] - sMean[r]) * sRstd[r] * l1g[dd] + l1b[dd];
  }
  __syncthreads();

  // ---- phase 2: FFN + residual + LN2 -> h2 ----
  {
    float a0[4], a1[4];
    const float b0 = f1b[tid], b1 = f1b[tid + 256];
    #pragma unroll
    for (int r = 0; r < 4; r++) { a0[r] = b0; a1[r] = b1; }
    for (int kk = 0; kk < 128; kk++) {
      const float w0 = f1wt[kk*512 + tid];
      const float w1 = f1wt[kk*512 + tid + 256];
      #pragma unroll
      for (int r = 0; r < 4; r++) {
        const float xv = sh[r][kk];
        a0[r] += w0 * xv;
        a1[r] += w1 * xv;
      }
    }
    #pragma unroll
    for (int r = 0; r < 4; r++) {
      sf[r][tid]       = fmaxf(a0[r], 0.f);
      sf[r][tid + 256] = fmaxf(a1[r], 0.f);
    }
  }
  __syncthreads();
  {
    float acc[2];
    #pragma unroll
    for (int rr = 0; rr < 2; rr++) acc[rr] = f2b[d];
    for (int kk = 0; kk < 512; kk++) {
      const float wv = f2wt[kk*128 + d];
      #pragma unroll
      for (int rr = 0; rr < 2; rr++) acc[rr] += wv * sf[r0 + rr][kk];
    }
    #pragma unroll
    for (int rr = 0; rr < 2; rr++)
      sV[r0 + rr][d] = sh[r0 + rr][d] + acc[rr];
  }
  __syncthreads();
  {
    const int r = tid >> 4, j = tid & 15;
    if (r < 4) {
      float p1 = 0.f, p2 = 0.f;
      #pragma unroll
      for (int i = 0; i < 8; i++) { float v = sV[r][j*8 + i]; p1 += v; p2 += v*v; }
      #pragma unroll
      for (int m = 8; m >= 1; m >>= 1) {
        p1 += __shfl_xor(p1, m, 64);
        p2 += __shfl_xor(p2, m, 64);
      }
      if (j == 0) {
        const float mean = p1 * (1.f/128.f);
        sMean[r] = mean;
        sRstd[r] = rsqrtf(p2 * (1.f/128.f) - mean*mean + 1e-5f);
      }
    }
  }
  __syncthreads();
  for (int idx = tid; idx < 4*128; idx += 256) {
    const int r = idx >> 7, dd = idx & 127;
    h2[((size_t)b*112 + s0 + r)*128 + dd] =
        (sV[r][dd] - sMean[r]) * sRstd[r] * l2g[dd] + l2b[dd];
  }
}

// ---------------- rep = sum_s h2 ; classifier -> logits (f32)
__global__ __launch_bounds__(64) void k_cls(
    const float* __restrict__ h2,
    const float* __restrict__ c1w, const float* __restrict__ c1b,
    const float* __restrict__ c2w, const float* __restrict__ c2b,
    float* __restrict__ out)
{
  __shared__ float sr[128], sc[64];
  const int b = blockIdx.x, tid = threadIdx.x;
  float r0 = 0.f, r1 = 0.f;
  for (int s2 = 0; s2 < 112; s2++) {
    const float* row = h2 + ((size_t)b*112 + s2)*128;
    r0 += row[tid];
    r1 += row[tid + 64];
  }
  sr[tid] = r0; sr[tid + 64] = r1;
  __syncthreads();
  float acc = c1b[tid];
  const float* wr = c1w + (size_t)tid * 128;
  for (int kk = 0; kk < 128; kk++) acc += wr[kk] * sr[kk];
  sc[tid] = fmaxf(acc, 0.f);
  __syncthreads();
  if (tid < 2) {
    float l = c2b[tid];
    for (int kk = 0; kk < 64; kk++) l += c2w[tid*64 + kk] * sc[kk];
    out[b*2 + tid] = l;
  }
}

extern "C" void kernel_launch(void* const* d_in, const int* in_sizes, int n_in,
                              void* d_out, int out_size, void* d_ws, size_t ws_size,
                              hipStream_t stream)
{
  const float* x    = (const float*)d_in[0];
  const float* c1w  = (const float*)d_in[1];
  const float* c1b  = (const float*)d_in[2];
  const float* bn1g = (const float*)d_in[3];
  const float* bn1b = (const float*)d_in[4];
  const float* c2w  = (const float*)d_in[5];
  const float* c2b  = (const float*)d_in[6];
  const float* bn2g = (const float*)d_in[7];
  const float* bn2b = (const float*)d_in[8];
  const float* pjw  = (const float*)d_in[9];
  const float* pjb  = (const float*)d_in[10];
  const float* w1w  = (const float*)d_in[11];
  const float* w1b  = (const float*)d_in[12];
  const float* w2w  = (const float*)d_in[13];
  const float* w2b  = (const float*)d_in[14];
  const float* gw   = (const float*)d_in[15];
  const float* gb   = (const float*)d_in[16];
  const float* scw  = (const float*)d_in[17];
  const float* scb  = (const float*)d_in[18];
  const float* ipw  = (const float*)d_in[19];
  const float* ipb  = (const float*)d_in[20];
  const float* opw  = (const float*)d_in[21];
  const float* opb  = (const float*)d_in[22];
  const float* f1w  = (const float*)d_in[23];
  const float* f1b  = (const float*)d_in[24];
  const float* f2w  = (const float*)d_in[25];
  const float* f2b  = (const float*)d_in[26];
  const float* l1g  = (const float*)d_in[27];
  const float* l1b  = (const float*)d_in[28];
  const float* l2g  = (const float*)d_in[29];
  const float* l2b  = (const float*)d_in[30];
  const float* cl1w = (const float*)d_in[31];
  const float* cl1b = (const float*)d_in[32];
  const float* cl2w = (const float*)d_in[33];
  const float* cl2b = (const float*)d_in[34];

  // ---- bump allocator over d_ws (256-B aligned) ----
  char* p = (char*)d_ws;
  auto alloc = [&](size_t n) { char* r = p; p += (n + 255) & ~(size_t)255; return r; };
  u64*   mask2  = (u64*)  alloc(900    * sizeof(u64));
  int*   nbr1   = (int*)  alloc(1800   * sizeof(int));
  int*   sel    = (int*)  alloc(1792   * sizeof(int));
  float* scores = (float*)alloc(3600   * sizeof(float));
  u16*   pwh    = (u16*)  alloc(524288 * sizeof(u16));
  u16*   pwl    = (u16*)  alloc(524288 * sizeof(u16));
  u16*   wc2h   = (u16*)  alloc(36864  * sizeof(u16));
  u16*   wc2l   = (u16*)  alloc(36864  * sizeof(u16));
  u16*   wc1h   = (u16*)  alloc(2048   * sizeof(u16));
  u16*   wc1l   = (u16*)  alloc(2048   * sizeof(u16));
  float* iwt    = (float*)alloc(49152  * sizeof(float));
  float* owt    = (float*)alloc(16384  * sizeof(float));
  float* f1wt   = (float*)alloc(65536  * sizeof(float));
  float* f2wt   = (float*)alloc(65536  * sizeof(float));
  float* w1t    = (float*)alloc(16384  * sizeof(float));
  float* w2t    = (float*)alloc(16384  * sizeof(float));
  float* gwt    = (float*)alloc(32768  * sizeof(float));
  float* partial= (float*)alloc(8ull*16*225*128 * sizeof(float));  // 14.7 MB split-K=8
  float* zbuf   = (float*)alloc(460800 * sizeof(float));
  float* nodes  = (float*)alloc(460800 * sizeof(float));
  const size_t fixed_bytes = (size_t)(p - (char*)d_ws);

  const size_t qkv_bytes = 3ull * 229376ull * sizeof(float);
  const size_t per_batch = 64ull*128*128*2 + 64ull*64*64*2;   // 2,621,440 B
  int BC = 16;
  size_t s3 = 0;
  for (;; BC >>= 1) {
    s3 = (size_t)BC * per_batch; if (s3 < qkv_bytes) s3 = qkv_bytes;
    if (fixed_bytes + s3 + 65536 <= ws_size) break;
    if (BC == 1) { return; }
  }
  char* S3 = alloc(s3);

  u16*   feat1 = (u16*)S3;                              // NHWC (BC,128,128,64)
  u16*   feat2 = (u16*)(S3 + (size_t)BC * 2097152ull);  // NCHW (BC,64,64,64)
  float* qb    = (float*)S3;
  float* kb    = qb + 229376;
  float* vb    = kb + 229376;
  float* obuf  = nodes;                                 // nodes dead after k_gz2
  float* hbuf  = nodes + 229376;                        // h2

  k_prep<<<1913, 256, 0, stream>>>(pjw, pwh, pwl, c2w, bn2g, wc2h, wc2l,
                                   c1w, bn1g, wc1h, wc1l,
                                   ipw, iwt, opw, owt, f1w, f1wt, f2w, f2wt,
                                   w1w, w1t, w2w, w2t, gw, gwt, nbr1);
  k_adj2<<<1, 256, 0, stream>>>(nbr1, mask2);

  for (int b0 = 0; b0 < 16; b0 += BC) {
    k_conv1m<<<dim3(16,16,BC), 256, 0, stream>>>(x, wc1h, wc1l, c1b, bn1g, bn1b, feat1, b0);
    k_conv2m<<<dim3(4,8,BC), 256, 0, stream>>>(feat1, wc2h, wc2l, c2b, bn2g, bn2b, feat2);
    k_projm <<<dim3(4,8,BC), 256, 0, stream>>>(feat2, pwh, pwl, partial, b0);
    k_projr <<<dim3(225,BC), 128, 0, stream>>>(partial, pjb, nodes, b0);
  }

  k_gz2  <<<900, 256, 0, stream>>>(nodes, nbr1, mask2, w1t, w1b, w2t, w2b,
                                   gwt, gb, scw, scb, zbuf, scores);
  k_topk <<<16, 256, 0, stream>>>(scores, sel);
  k_qkv  <<<dim3(28,16), 256, 0, stream>>>(zbuf, sel, iwt, ipb, qb, kb, vb);
  k_attn <<<dim3(8,4,16), 256, 0, stream>>>(qb, kb, vb, obuf);
  k_tail <<<dim3(28,16), 256, 0, stream>>>(obuf, zbuf, sel, owt, opb, l1g, l1b,
                                           f1wt, f1b, f2wt, f2b, l2g, l2b, hbuf);
  k_cls  <<<16, 64, 0, stream>>>(hbuf, cl1w, cl1b, cl2w, cl2b, (float*)d_out);
}